// Round 8
// baseline (1837.943 us; speedup 1.0000x reference)
//
#include <hip/hip_runtime.h>

#define N_NODES 100000
#define N_EDGES 1600000
#define NB 64
#define NI 64
#define EI 32
#define GI 32
#define NO 32
#define EO 32
#define GO 32
#define HH 3
#define HNO 96   /* H*NO */
#define NEG 0.2f
#define SCAN_BLKS 98   /* ceil(100000/1024) */
#define WPITCH 36      /* padded row pitch for transposed weights: 16B-aligned, 4-way conflict */

// ---------------- KA: fused node transforms, register-blocked ----------------
__global__ __launch_bounds__(256) void kA_node(
    const float* __restrict__ x,
    const float* __restrict__ W_l, const float* __restrict__ b_l,
    const float* __restrict__ W_r, const float* __restrict__ b_r,
    const float* __restrict__ W_edge, const float* __restrict__ b_edge,
    float* __restrict__ xl, float* __restrict__ xr, float* __restrict__ pre_e,
    int niters)
{
    __shared__ float sWl[NI * HNO];   // 24 KB
    __shared__ float sWr[NI * HNO];   // 24 KB
    __shared__ float sWp[NI * 32];    // 8 KB  (W_edge rows 0..63)
    __shared__ float sx[64 * NI];     // 16 KB
    int t = threadIdx.x;
    for (int f = t; f < NI * HNO; f += 256) { sWl[f] = W_l[f]; sWr[f] = W_r[f]; }
    for (int f = t; f < NI * 32; f += 256) sWp[f] = W_edge[f];
    __syncthreads();
    int k = t & 31, g = t >> 5;
    float bl0 = b_l[k], bl1 = b_l[k + 32], bl2 = b_l[k + 64];
    float br0 = b_r[k], br1 = b_r[k + 32], br2 = b_r[k + 64];
    float bpe = b_edge[k];
    const long NX = (long)N_NODES * NI;
    for (int it = 0; it < niters; ++it) {
        long nb = ((long)blockIdx.x + (long)it * gridDim.x) * 64;
        long base = nb * NI;
        for (int f = t; f < 64 * NI; f += 256) {
            long idx = base + f;
            sx[f] = x[idx < NX ? idx : 0];
        }
        __syncthreads();
        float aL0[8], aL1[8], aL2[8], aR0[8], aR1[8], aR2[8], aP[8];
        #pragma unroll
        for (int m = 0; m < 8; ++m) {
            aL0[m] = bl0; aL1[m] = bl1; aL2[m] = bl2;
            aR0[m] = br0; aR1[m] = br1; aR2[m] = br2;
            aP[m] = bpe;
        }
        const float* sxg = &sx[g * 8 * NI];
        for (int i = 0; i < NI; ++i) {
            float wl0 = sWl[i * HNO + k], wl1 = sWl[i * HNO + 32 + k], wl2 = sWl[i * HNO + 64 + k];
            float wr0 = sWr[i * HNO + k], wr1 = sWr[i * HNO + 32 + k], wr2 = sWr[i * HNO + 64 + k];
            float wp  = sWp[i * 32 + k];
            #pragma unroll
            for (int m = 0; m < 8; ++m) {
                float xv = sxg[m * NI + i];
                aL0[m] += xv * wl0; aL1[m] += xv * wl1; aL2[m] += xv * wl2;
                aR0[m] += xv * wr0; aR1[m] += xv * wr1; aR2[m] += xv * wr2;
                aP[m]  += xv * wp;
            }
        }
        #pragma unroll
        for (int m = 0; m < 8; ++m) {
            long n = nb + g * 8 + m;
            if (n < N_NODES) {
                xl[n * HNO + k]      = aL0[m];
                xl[n * HNO + 32 + k] = aL1[m];
                xl[n * HNO + 64 + k] = aL2[m];
                xr[n * HNO + k]      = aR0[m];
                xr[n * HNO + 32 + k] = aR1[m];
                xr[n * HNO + 64 + k] = aR2[m];
                pre_e[n * 32 + k]    = aP[m];
            }
        }
        __syncthreads();
    }
}

// ---------------- K_hist: cnt[dst]++ ----------------
__global__ __launch_bounds__(256) void k_hist(const int* __restrict__ eidx, int* __restrict__ cnt)
{
    long i = (long)blockIdx.x * 256 + threadIdx.x;
    long stride = (long)gridDim.x * 256;
    for (; i < N_EDGES; i += stride)
        atomicAdd(&cnt[eidx[N_EDGES + i]], 1);
}

// ---------------- parallel scan: per-block sums ----------------
__global__ __launch_bounds__(1024) void k_scan1(const int* __restrict__ cnt, int* __restrict__ bsum)
{
    __shared__ int s[1024];
    int i = blockIdx.x * 1024 + threadIdx.x;
    s[threadIdx.x] = (i < N_NODES) ? cnt[i] : 0;
    for (int o = 512; o > 0; o >>= 1) {
        __syncthreads();
        if (threadIdx.x < o) s[threadIdx.x] += s[threadIdx.x + o];
    }
    if (threadIdx.x == 0) bsum[blockIdx.x] = s[0];
}

// ---------------- scan of the 98 block sums -> exclusive bases (in place) ----------------
__global__ __launch_bounds__(128) void k_scan2(int* __restrict__ bsum)
{
    __shared__ int s[128];
    int v = (threadIdx.x < SCAN_BLKS) ? bsum[threadIdx.x] : 0;
    s[threadIdx.x] = v;
    for (int o = 1; o < 128; o <<= 1) {
        __syncthreads();
        int a = (threadIdx.x >= o) ? s[threadIdx.x - o] : 0;
        __syncthreads();
        s[threadIdx.x] += a;
    }
    if (threadIdx.x < SCAN_BLKS) bsum[threadIdx.x] = s[threadIdx.x] - v;  // exclusive base
}

// ---------------- per-block rescan + write off/cursor ----------------
__global__ __launch_bounds__(1024) void k_scan3(const int* __restrict__ cnt,
                                                const int* __restrict__ bsum,
                                                int* __restrict__ off, int* __restrict__ cursor)
{
    __shared__ int s[1024];
    int i = blockIdx.x * 1024 + threadIdx.x;
    int v = (i < N_NODES) ? cnt[i] : 0;
    s[threadIdx.x] = v;
    for (int o = 1; o < 1024; o <<= 1) {
        __syncthreads();
        int a = (threadIdx.x >= o) ? s[threadIdx.x - o] : 0;
        __syncthreads();
        s[threadIdx.x] += a;
    }
    int excl = bsum[blockIdx.x] + s[threadIdx.x] - v;
    if (i < N_NODES) {
        off[i] = excl; cursor[i] = excl;
        if (i == N_NODES - 1) off[N_NODES] = excl + v;
    }
}

// ---------------- K_scatter: CSR {eid, src} pairs grouped by dst ----------------
__global__ __launch_bounds__(256) void k_scatter(const int* __restrict__ eidx,
                                                 int* __restrict__ cursor,
                                                 int2* __restrict__ ep)
{
    long i = (long)blockIdx.x * 256 + threadIdx.x;
    long stride = (long)gridDim.x * 256;
    for (; i < N_EDGES; i += stride) {
        int s = eidx[i];
        int d = eidx[N_EDGES + i];
        int pos = atomicAdd(&cursor[d], 1);
        ep[pos] = make_int2((int)i, s);
    }
}

// ---------------- KF: dst-ordered fused edge pass, dual-edge, b128 weight reads ----------------
// Transposed weight layouts (per-lane row, pitch WPITCH=36, 16B-aligned) let each lane
// read 4 i-steps of weights per ds_read_b128; ea/eo staged per-edge-contiguous so
// uniform-address float4 reads broadcast 4 i-steps. Fused node_mlp_2 tail (writes x_new).
__global__ __launch_bounds__(256) void kF(
    const float* __restrict__ pre_e, const float* __restrict__ ea,
    const float* __restrict__ W_edge, const float* __restrict__ W_e,
    const float* __restrict__ att,
    const float* __restrict__ xl, const float* __restrict__ xr,
    const int2* __restrict__ ep, const int* __restrict__ off,
    const float* __restrict__ bias_gat, const float* __restrict__ glob,
    const int* __restrict__ batch, const float* __restrict__ W_n2,
    const float* __restrict__ b_n2,
    float* __restrict__ e_out, float* __restrict__ x_new, int niters)
{
    __shared__ __align__(16) float sW2T[32 * WPITCH];      // 4.6 KB  [k][i] = W_edge[(64+i)*32+k]
    __shared__ __align__(16) float sWeT[3][32 * WPITCH];   // 13.8 KB [h][k][i] = W_e[i*96+h*32+k]
    __shared__ __align__(16) float sEaA[8][32];            // per-group staging, edge A
    __shared__ __align__(16) float sEaB[8][32];            // edge B
    __shared__ __align__(16) float sEoA[8][32];
    __shared__ __align__(16) float sEoB[8][32];
    __shared__ float sWn[128 * 32];                        // 16 KB node_mlp_2 weights
    __shared__ float sG[8][128];                           // 4 KB tail staging
    int t = threadIdx.x;
    for (int f = t; f < 1024; f += 256) {
        int kk = f >> 5, ii = f & 31;
        sW2T[kk * WPITCH + ii] = W_edge[(64 + ii) * 32 + kk];
    }
    for (int f = t; f < 3072; f += 256) {
        int h = f >> 10, r = f & 1023;
        int kk = r >> 5, ii = r & 31;
        sWeT[h][kk * WPITCH + ii] = W_e[ii * 96 + h * 32 + kk];
    }
    for (int f = t; f < 128 * 32; f += 256) sWn[f] = W_n2[f];
    __syncthreads();
    int k = t & 31, gid = t >> 5;
    float at0 = att[k], at1 = att[32 + k], at2 = att[64 + k];
    float bg0 = bias_gat[k], bg1 = bias_gat[32 + k], bg2 = bias_gat[64 + k];
    float bn = b_n2[k];
    const float4* w2p = (const float4*)&sW2T[k * WPITCH];
    const float4* we0p = (const float4*)&sWeT[0][k * WPITCH];
    const float4* we1p = (const float4*)&sWeT[1][k * WPITCH];
    const float4* we2p = (const float4*)&sWeT[2][k * WPITCH];
    const float4* eaAp = (const float4*)&sEaA[gid][0];
    const float4* eaBp = (const float4*)&sEaB[gid][0];
    const float4* eoAp = (const float4*)&sEoA[gid][0];
    const float4* eoBp = (const float4*)&sEoB[gid][0];
    for (int it = 0; it < niters; ++it) {
        long n = ((long)blockIdx.x + (long)it * gridDim.x) * 8 + gid;
        if (n >= N_NODES) continue;
        int lo = off[n], hi = off[n + 1];
        float xr0 = xr[n * HNO + k];
        float xr1 = xr[n * HNO + 32 + k];
        float xr2 = xr[n * HNO + 64 + k];
        float a0 = 0.f, a1 = 0.f, a2 = 0.f;
        float d0 = 0.f, d1 = 0.f, d2 = 0.f;
        int deg = hi - lo;
        int steps = (deg + 1) >> 1;
        int eA = 0, sA = 0, eB = 0, sB = 0;
        int eA1 = 0, sA1 = 0, eB1 = 0, sB1 = 0;
        float peA = 0.f, peB = 0.f, eaAv = 0.f, eaBv = 0.f;
        float xlA0 = 0.f, xlA1 = 0.f, xlA2 = 0.f, xlB0 = 0.f, xlB1 = 0.f, xlB2 = 0.f;
        if (steps > 0) {
            int2 q = ep[lo]; eA = q.x; sA = q.y;
            if (lo + 1 < hi) { int2 r = ep[lo + 1]; eB = r.x; sB = r.y; }
            peA = pre_e[(long)sA * 32 + k];   peB = pre_e[(long)sB * 32 + k];
            eaAv = ea[(long)eA * EI + k];     eaBv = ea[(long)eB * EI + k];
            xlA0 = xl[(long)sA * HNO + k]; xlA1 = xl[(long)sA * HNO + 32 + k]; xlA2 = xl[(long)sA * HNO + 64 + k];
            xlB0 = xl[(long)sB * HNO + k]; xlB1 = xl[(long)sB * HNO + 32 + k]; xlB2 = xl[(long)sB * HNO + 64 + k];
            if (lo + 2 < hi) { int2 q1 = ep[lo + 2]; eA1 = q1.x; sA1 = q1.y; }
            if (lo + 3 < hi) { int2 r1 = ep[lo + 3]; eB1 = r1.x; sB1 = r1.y; }
        }
        for (int st = 0; st < steps; ++st) {
            // prefetch next-pair data (clamped-id defaults harmless)
            float peA_n = pre_e[(long)sA1 * 32 + k], peB_n = pre_e[(long)sB1 * 32 + k];
            float eaA_n = ea[(long)eA1 * EI + k],    eaB_n = ea[(long)eB1 * EI + k];
            float xlA0n = xl[(long)sA1 * HNO + k], xlA1n = xl[(long)sA1 * HNO + 32 + k], xlA2n = xl[(long)sA1 * HNO + 64 + k];
            float xlB0n = xl[(long)sB1 * HNO + k], xlB1n = xl[(long)sB1 * HNO + 32 + k], xlB2n = xl[(long)sB1 * HNO + 64 + k];
            int eA2 = 0, sA2 = 0, eB2 = 0, sB2 = 0;
            int pA2 = lo + 2 * st + 4;
            if (pA2 < hi)     { int2 q2 = ep[pA2];     eA2 = q2.x; sA2 = q2.y; }
            if (pA2 + 1 < hi) { int2 r2 = ep[pA2 + 1]; eB2 = r2.x; sB2 = r2.y; }
            // ---- edge MLP (dual, b128 reads) ----
            sEaA[gid][k] = eaAv;
            sEaB[gid][k] = eaBv;
            float accA = peA, accB = peB;
            #pragma unroll
            for (int i4 = 0; i4 < 8; ++i4) {
                float4 w  = w2p[i4];
                float4 a4 = eaAp[i4];
                float4 b4 = eaBp[i4];
                accA += a4.x * w.x + a4.y * w.y + a4.z * w.z + a4.w * w.w;
                accB += b4.x * w.x + b4.y * w.y + b4.z * w.z + b4.w * w.w;
            }
            float eoA = fmaxf(accA, 0.f), eoB = fmaxf(accB, 0.f);
            bool okB = (lo + 2 * st + 1) < hi;
            e_out[(long)eA * EO + k] = eoA;
            if (okB) e_out[(long)eB * EO + k] = eoB;
            sEoA[gid][k] = eoA;
            sEoB[gid][k] = eoB;
            // ---- h = xl + xr + eo@We (dual, b128 reads) ----
            float hA0 = xlA0 + xr0, hA1 = xlA1 + xr1, hA2 = xlA2 + xr2;
            float hB0 = xlB0 + xr0, hB1 = xlB1 + xr1, hB2 = xlB2 + xr2;
            #pragma unroll
            for (int i4 = 0; i4 < 8; ++i4) {
                float4 oA = eoAp[i4];
                float4 oB = eoBp[i4];
                float4 w0 = we0p[i4], w1 = we1p[i4], w2v = we2p[i4];
                hA0 += oA.x * w0.x + oA.y * w0.y + oA.z * w0.z + oA.w * w0.w;
                hA1 += oA.x * w1.x + oA.y * w1.y + oA.z * w1.z + oA.w * w1.w;
                hA2 += oA.x * w2v.x + oA.y * w2v.y + oA.z * w2v.z + oA.w * w2v.w;
                hB0 += oB.x * w0.x + oB.y * w0.y + oB.z * w0.z + oB.w * w0.w;
                hB1 += oB.x * w1.x + oB.y * w1.y + oB.z * w1.z + oB.w * w1.w;
                hB2 += oB.x * w2v.x + oB.y * w2v.y + oB.z * w2v.z + oB.w * w2v.w;
            }
            float pA0 = (hA0 > 0.f ? hA0 : NEG * hA0) * at0;
            float pA1 = (hA1 > 0.f ? hA1 : NEG * hA1) * at1;
            float pA2v = (hA2 > 0.f ? hA2 : NEG * hA2) * at2;
            float pB0 = (hB0 > 0.f ? hB0 : NEG * hB0) * at0;
            float pB1 = (hB1 > 0.f ? hB1 : NEG * hB1) * at1;
            float pB2 = (hB2 > 0.f ? hB2 : NEG * hB2) * at2;
            #pragma unroll
            for (int m = 1; m <= 16; m <<= 1) {
                pA0 += __shfl_xor(pA0, m, 32); pA1 += __shfl_xor(pA1, m, 32); pA2v += __shfl_xor(pA2v, m, 32);
                pB0 += __shfl_xor(pB0, m, 32); pB1 += __shfl_xor(pB1, m, 32); pB2 += __shfl_xor(pB2, m, 32);
            }
            float exA0 = __expf(pA0), exA1 = __expf(pA1), exA2 = __expf(pA2v);
            float exB0 = 0.f, exB1 = 0.f, exB2 = 0.f;
            if (okB) { exB0 = __expf(pB0); exB1 = __expf(pB1); exB2 = __expf(pB2); }
            a0 += exA0 * xlA0; a1 += exA1 * xlA1; a2 += exA2 * xlA2;
            a0 += exB0 * xlB0; a1 += exB1 * xlB1; a2 += exB2 * xlB2;
            d0 += exA0 + exB0; d1 += exA1 + exB1; d2 += exA2 + exB2;
            // rotate pipeline
            eA = eA1; sA = sA1; eB = eB1; sB = sB1;
            eA1 = eA2; sA1 = sA2; eB1 = eB2; sB1 = sB2;
            peA = peA_n; peB = peB_n; eaAv = eaA_n; eaBv = eaB_n;
            xlA0 = xlA0n; xlA1 = xlA1n; xlA2 = xlA2n;
            xlB0 = xlB0n; xlB1 = xlB1n; xlB2 = xlB2n;
        }
        // ---- fused node_mlp_2 tail ----
        float g0 = (d0 > 0.f ? a0 / d0 : 0.f) + bg0;
        float g1 = (d1 > 0.f ? a1 / d1 : 0.f) + bg1;
        float g2 = (d2 > 0.f ? a2 / d2 : 0.f) + bg2;
        float gg = glob[(long)batch[n] * GI + k];
        sG[gid][k] = g0; sG[gid][32 + k] = g1; sG[gid][64 + k] = g2; sG[gid][96 + k] = gg;
        float acc2 = bn;
        #pragma unroll 8
        for (int i = 0; i < 128; ++i) acc2 += sG[gid][i] * sWn[i * 32 + k];
        x_new[n * NO + k] = fmaxf(acc2, 0.f);
    }
}

// ---------------- K3: per-graph mean of x_new (batch sorted), then global MLP ----------------
__device__ __forceinline__ int lower_bound_dev(const int* __restrict__ a, int n, int v) {
    int lo = 0, hi = n;
    while (lo < hi) { int mid = (lo + hi) >> 1; if (a[mid] < v) lo = mid + 1; else hi = mid; }
    return lo;
}

__global__ __launch_bounds__(256) void k3_global(
    const float* __restrict__ x_new, const int* __restrict__ batch,
    const float* __restrict__ glob, const float* __restrict__ W_g,
    const float* __restrict__ b_g, float* __restrict__ u_new)
{
    __shared__ int s_lo, s_hi;
    __shared__ float s_part[8][32];
    __shared__ float s_mean[32];
    int g = blockIdx.x;
    if (threadIdx.x == 0) {
        s_lo = lower_bound_dev(batch, N_NODES, g);
        s_hi = lower_bound_dev(batch, N_NODES, g + 1);
    }
    __syncthreads();
    int lo = s_lo, hi = s_hi;
    int k = threadIdx.x & 31, c = threadIdx.x >> 5;
    float acc = 0.f;
    for (long n = lo + c; n < hi; n += 8) acc += x_new[n * NO + k];
    s_part[c][k] = acc;
    __syncthreads();
    if (threadIdx.x < 32) {
        float s = 0.f;
        #pragma unroll
        for (int c2 = 0; c2 < 8; ++c2) s += s_part[c2][k];
        int cnt = hi - lo;
        s_mean[k] = s / (float)(cnt > 0 ? cnt : 1);
    }
    __syncthreads();
    if (threadIdx.x < 32) {
        float acc2 = b_g[k];
        #pragma unroll
        for (int i = 0; i < 32; ++i) acc2 += glob[g * GI + i] * W_g[i * GO + k];
        #pragma unroll
        for (int i = 0; i < 32; ++i) acc2 += s_mean[i] * W_g[(32 + i) * GO + k];
        u_new[g * GO + k] = fmaxf(acc2, 0.f);
    }
}

extern "C" void kernel_launch(void* const* d_in, const int* in_sizes, int n_in,
                              void* d_out, int out_size, void* d_ws, size_t ws_size,
                              hipStream_t stream) {
    const float* x        = (const float*)d_in[0];
    const float* edge_attr= (const float*)d_in[1];
    const float* glob     = (const float*)d_in[2];
    const float* W_edge   = (const float*)d_in[3];
    const float* b_edge   = (const float*)d_in[4];
    const float* W_l      = (const float*)d_in[5];
    const float* b_l      = (const float*)d_in[6];
    const float* W_r      = (const float*)d_in[7];
    const float* b_r      = (const float*)d_in[8];
    const float* W_e      = (const float*)d_in[9];
    const float* att      = (const float*)d_in[10];
    const float* bias_gat = (const float*)d_in[11];
    const float* W_n2     = (const float*)d_in[12];
    const float* b_n2     = (const float*)d_in[13];
    const float* W_g      = (const float*)d_in[14];
    const float* b_g      = (const float*)d_in[15];
    const int* edge_index = (const int*)d_in[16];
    const int* batch      = (const int*)d_in[17];

    float* out   = (float*)d_out;
    float* x_new = out;                                    // N*32
    float* e_out = out + (size_t)N_NODES * NO;             // E*32
    float* u_new = e_out + (size_t)N_EDGES * EO;           // B*32

    // workspace layout (floats before ep sum to N*224 -> ep stays 8B-aligned)
    float*  ws    = (float*)d_ws;
    float*  xl    = ws;                                    // N*96
    float*  xr    = xl + (size_t)N_NODES * HNO;            // N*96
    float*  pre_e = xr + (size_t)N_NODES * HNO;            // N*32
    int2*   ep    = (int2*)(pre_e + (size_t)N_NODES * 32); // E int2
    int*    cnt   = (int*)(ep + (size_t)N_EDGES);          // N
    int*    off   = cnt + N_NODES;                         // N+1
    int*    cursor= off + N_NODES + 1;                     // N
    int*    bsum  = cursor + N_NODES;                      // 128

    hipMemsetAsync(cnt, 0, (size_t)N_NODES * sizeof(int), stream);

    // CSR build (parallel scan)
    k_hist<<<1024, 256, 0, stream>>>(edge_index, cnt);
    k_scan1<<<SCAN_BLKS, 1024, 0, stream>>>(cnt, bsum);
    k_scan2<<<1, 128, 0, stream>>>(bsum);
    k_scan3<<<SCAN_BLKS, 1024, 0, stream>>>(cnt, bsum, off, cursor);
    k_scatter<<<1024, 256, 0, stream>>>(edge_index, cursor, ep);

    // node transforms (xl, xr, pre_e in one pass over x)
    int gridA = 1024;
    int groups64 = (N_NODES + 63) / 64;                    // 1563
    int itA = (groups64 + gridA - 1) / gridA;              // 2
    kA_node<<<gridA, 256, 0, stream>>>(x, W_l, b_l, W_r, b_r, W_edge, b_edge,
                                       xl, xr, pre_e, itA);

    // fused edge pass + aggregation + node_mlp_2 (dual-edge, b128 weights)
    int gridF = 2048;
    int groups8 = (N_NODES + 7) / 8;                       // 12500
    int itF = (groups8 + gridF - 1) / gridF;               // 7
    kF<<<gridF, 256, 0, stream>>>(pre_e, edge_attr, W_edge, W_e, att, xl, xr,
                                  ep, off, bias_gat, glob, batch, W_n2, b_n2,
                                  e_out, x_new, itF);

    k3_global<<<NB, 256, 0, stream>>>(x_new, batch, glob, W_g, b_g, u_new);
}

// Round 9
// 1351.231 us; speedup vs baseline: 1.3602x; 1.3602x over previous
//
#include <hip/hip_runtime.h>

#define N_NODES 100000
#define N_EDGES 1600000
#define NB 64
#define NI 64
#define EI 32
#define GI 32
#define NO 32
#define EO 32
#define GO 32
#define HH 3
#define HNO 96   /* H*NO */
#define NEG 0.2f
#define SCAN_BLKS 98   /* ceil(100000/1024) */
#define WPITCH 36      /* transposed-weight row pitch: 144B = 16B-aligned, 4-way conflict on b128 */

// ---------------- KA: fused node transforms, register-blocked ----------------
__global__ __launch_bounds__(256) void kA_node(
    const float* __restrict__ x,
    const float* __restrict__ W_l, const float* __restrict__ b_l,
    const float* __restrict__ W_r, const float* __restrict__ b_r,
    const float* __restrict__ W_edge, const float* __restrict__ b_edge,
    float* __restrict__ xl, float* __restrict__ xr, float* __restrict__ pre_e,
    int niters)
{
    __shared__ float sWl[NI * HNO];   // 24 KB
    __shared__ float sWr[NI * HNO];   // 24 KB
    __shared__ float sWp[NI * 32];    // 8 KB  (W_edge rows 0..63)
    __shared__ float sx[64 * NI];     // 16 KB
    int t = threadIdx.x;
    for (int f = t; f < NI * HNO; f += 256) { sWl[f] = W_l[f]; sWr[f] = W_r[f]; }
    for (int f = t; f < NI * 32; f += 256) sWp[f] = W_edge[f];
    __syncthreads();
    int k = t & 31, g = t >> 5;
    float bl0 = b_l[k], bl1 = b_l[k + 32], bl2 = b_l[k + 64];
    float br0 = b_r[k], br1 = b_r[k + 32], br2 = b_r[k + 64];
    float bpe = b_edge[k];
    const long NX = (long)N_NODES * NI;
    for (int it = 0; it < niters; ++it) {
        long nb = ((long)blockIdx.x + (long)it * gridDim.x) * 64;
        long base = nb * NI;
        for (int f = t; f < 64 * NI; f += 256) {
            long idx = base + f;
            sx[f] = x[idx < NX ? idx : 0];
        }
        __syncthreads();
        float aL0[8], aL1[8], aL2[8], aR0[8], aR1[8], aR2[8], aP[8];
        #pragma unroll
        for (int m = 0; m < 8; ++m) {
            aL0[m] = bl0; aL1[m] = bl1; aL2[m] = bl2;
            aR0[m] = br0; aR1[m] = br1; aR2[m] = br2;
            aP[m] = bpe;
        }
        const float* sxg = &sx[g * 8 * NI];
        for (int i = 0; i < NI; ++i) {
            float wl0 = sWl[i * HNO + k], wl1 = sWl[i * HNO + 32 + k], wl2 = sWl[i * HNO + 64 + k];
            float wr0 = sWr[i * HNO + k], wr1 = sWr[i * HNO + 32 + k], wr2 = sWr[i * HNO + 64 + k];
            float wp  = sWp[i * 32 + k];
            #pragma unroll
            for (int m = 0; m < 8; ++m) {
                float xv = sxg[m * NI + i];
                aL0[m] += xv * wl0; aL1[m] += xv * wl1; aL2[m] += xv * wl2;
                aR0[m] += xv * wr0; aR1[m] += xv * wr1; aR2[m] += xv * wr2;
                aP[m]  += xv * wp;
            }
        }
        #pragma unroll
        for (int m = 0; m < 8; ++m) {
            long n = nb + g * 8 + m;
            if (n < N_NODES) {
                xl[n * HNO + k]      = aL0[m];
                xl[n * HNO + 32 + k] = aL1[m];
                xl[n * HNO + 64 + k] = aL2[m];
                xr[n * HNO + k]      = aR0[m];
                xr[n * HNO + 32 + k] = aR1[m];
                xr[n * HNO + 64 + k] = aR2[m];
                pre_e[n * 32 + k]    = aP[m];
            }
        }
        __syncthreads();
    }
}

// ---------------- K_hist: cnt[dst]++ ----------------
__global__ __launch_bounds__(256) void k_hist(const int* __restrict__ eidx, int* __restrict__ cnt)
{
    long i = (long)blockIdx.x * 256 + threadIdx.x;
    long stride = (long)gridDim.x * 256;
    for (; i < N_EDGES; i += stride)
        atomicAdd(&cnt[eidx[N_EDGES + i]], 1);
}

// ---------------- parallel scan: per-block sums ----------------
__global__ __launch_bounds__(1024) void k_scan1(const int* __restrict__ cnt, int* __restrict__ bsum)
{
    __shared__ int s[1024];
    int i = blockIdx.x * 1024 + threadIdx.x;
    s[threadIdx.x] = (i < N_NODES) ? cnt[i] : 0;
    for (int o = 512; o > 0; o >>= 1) {
        __syncthreads();
        if (threadIdx.x < o) s[threadIdx.x] += s[threadIdx.x + o];
    }
    if (threadIdx.x == 0) bsum[blockIdx.x] = s[0];
}

// ---------------- scan of the 98 block sums -> exclusive bases (in place) ----------------
__global__ __launch_bounds__(128) void k_scan2(int* __restrict__ bsum)
{
    __shared__ int s[128];
    int v = (threadIdx.x < SCAN_BLKS) ? bsum[threadIdx.x] : 0;
    s[threadIdx.x] = v;
    for (int o = 1; o < 128; o <<= 1) {
        __syncthreads();
        int a = (threadIdx.x >= o) ? s[threadIdx.x - o] : 0;
        __syncthreads();
        s[threadIdx.x] += a;
    }
    if (threadIdx.x < SCAN_BLKS) bsum[threadIdx.x] = s[threadIdx.x] - v;  // exclusive base
}

// ---------------- per-block rescan + write off/cursor ----------------
__global__ __launch_bounds__(1024) void k_scan3(const int* __restrict__ cnt,
                                                const int* __restrict__ bsum,
                                                int* __restrict__ off, int* __restrict__ cursor)
{
    __shared__ int s[1024];
    int i = blockIdx.x * 1024 + threadIdx.x;
    int v = (i < N_NODES) ? cnt[i] : 0;
    s[threadIdx.x] = v;
    for (int o = 1; o < 1024; o <<= 1) {
        __syncthreads();
        int a = (threadIdx.x >= o) ? s[threadIdx.x - o] : 0;
        __syncthreads();
        s[threadIdx.x] += a;
    }
    int excl = bsum[blockIdx.x] + s[threadIdx.x] - v;
    if (i < N_NODES) {
        off[i] = excl; cursor[i] = excl;
        if (i == N_NODES - 1) off[N_NODES] = excl + v;
    }
}

// ---------------- K_scatter: CSR {eid, src} pairs grouped by dst ----------------
__global__ __launch_bounds__(256) void k_scatter(const int* __restrict__ eidx,
                                                 int* __restrict__ cursor,
                                                 int2* __restrict__ ep)
{
    long i = (long)blockIdx.x * 256 + threadIdx.x;
    long stride = (long)gridDim.x * 256;
    for (; i < N_EDGES; i += stride) {
        int s = eidx[i];
        int d = eidx[N_EDGES + i];
        int pos = atomicAdd(&cursor[d], 1);
        ep[pos] = make_int2((int)i, s);
    }
}

// ---------------- KF: dst-ordered fused edge pass, dual-edge ----------------
// R7 structure (proven 683 us) with ONE change: weights read as float4 from a
// transposed pitch-36 LDS layout (4 i-steps per ds_read_b128). Staging reads stay
// uniform-address float2 broadcasts (conflict-free). Tail writes g_out; node_mlp_2
// stays in K2 (R8 showed fusing it collapses occupancy).
__global__ __launch_bounds__(256) void kF(
    const float* __restrict__ pre_e, const float* __restrict__ ea,
    const float* __restrict__ W_edge, const float* __restrict__ W_e,
    const float* __restrict__ att,
    const float* __restrict__ xl, const float* __restrict__ xr,
    const int2* __restrict__ ep, const int* __restrict__ off,
    const float* __restrict__ bias_gat,
    float* __restrict__ e_out, float* __restrict__ g_out, int niters)
{
    __shared__ __align__(16) float sW2T[32 * WPITCH];      // 4.6 KB  [k][i] = W_edge[(64+i)*32+k]
    __shared__ __align__(16) float sWeT[3][32 * WPITCH];   // 13.8 KB [h][k][i] = W_e[i*96+h*32+k]
    __shared__ float2 sEa2[8][32];                         // 2 KB dual staging (A,B)
    __shared__ float2 sEo2[8][32];                         // 2 KB
    int t = threadIdx.x;
    for (int f = t; f < 1024; f += 256) {
        int kk = f >> 5, ii = f & 31;
        sW2T[kk * WPITCH + ii] = W_edge[(64 + ii) * 32 + kk];
    }
    for (int f = t; f < 3072; f += 256) {
        int h = f >> 10, r = f & 1023;
        int kk = r >> 5, ii = r & 31;
        sWeT[h][kk * WPITCH + ii] = W_e[ii * 96 + h * 32 + kk];
    }
    __syncthreads();
    int k = t & 31, gid = t >> 5;
    float at0 = att[k], at1 = att[32 + k], at2 = att[64 + k];
    float bg0 = bias_gat[k], bg1 = bias_gat[32 + k], bg2 = bias_gat[64 + k];
    const float4* w2p  = (const float4*)&sW2T[k * WPITCH];
    const float4* we0p = (const float4*)&sWeT[0][k * WPITCH];
    const float4* we1p = (const float4*)&sWeT[1][k * WPITCH];
    const float4* we2p = (const float4*)&sWeT[2][k * WPITCH];
    for (int it = 0; it < niters; ++it) {
        long n = ((long)blockIdx.x + (long)it * gridDim.x) * 8 + gid;
        if (n >= N_NODES) continue;
        int lo = off[n], hi = off[n + 1];
        float xr0 = xr[n * HNO + k];
        float xr1 = xr[n * HNO + 32 + k];
        float xr2 = xr[n * HNO + 64 + k];
        float a0 = 0.f, a1 = 0.f, a2 = 0.f;
        float d0 = 0.f, d1 = 0.f, d2 = 0.f;
        int deg = hi - lo;
        int steps = (deg + 1) >> 1;
        int eA = 0, sA = 0, eB = 0, sB = 0;
        int eA1 = 0, sA1 = 0, eB1 = 0, sB1 = 0;
        float peA = 0.f, peB = 0.f, eaAv = 0.f, eaBv = 0.f;
        float xlA0 = 0.f, xlA1 = 0.f, xlA2 = 0.f, xlB0 = 0.f, xlB1 = 0.f, xlB2 = 0.f;
        if (steps > 0) {
            int2 q = ep[lo]; eA = q.x; sA = q.y;
            if (lo + 1 < hi) { int2 r = ep[lo + 1]; eB = r.x; sB = r.y; }
            peA = pre_e[(long)sA * 32 + k];   peB = pre_e[(long)sB * 32 + k];
            eaAv = ea[(long)eA * EI + k];     eaBv = ea[(long)eB * EI + k];
            xlA0 = xl[(long)sA * HNO + k]; xlA1 = xl[(long)sA * HNO + 32 + k]; xlA2 = xl[(long)sA * HNO + 64 + k];
            xlB0 = xl[(long)sB * HNO + k]; xlB1 = xl[(long)sB * HNO + 32 + k]; xlB2 = xl[(long)sB * HNO + 64 + k];
            if (lo + 2 < hi) { int2 q1 = ep[lo + 2]; eA1 = q1.x; sA1 = q1.y; }
            if (lo + 3 < hi) { int2 r1 = ep[lo + 3]; eB1 = r1.x; sB1 = r1.y; }
        }
        for (int st = 0; st < steps; ++st) {
            // prefetch next-pair data (clamped-id defaults harmless)
            float peA_n = pre_e[(long)sA1 * 32 + k], peB_n = pre_e[(long)sB1 * 32 + k];
            float eaA_n = ea[(long)eA1 * EI + k],    eaB_n = ea[(long)eB1 * EI + k];
            float xlA0n = xl[(long)sA1 * HNO + k], xlA1n = xl[(long)sA1 * HNO + 32 + k], xlA2n = xl[(long)sA1 * HNO + 64 + k];
            float xlB0n = xl[(long)sB1 * HNO + k], xlB1n = xl[(long)sB1 * HNO + 32 + k], xlB2n = xl[(long)sB1 * HNO + 64 + k];
            int eA2 = 0, sA2 = 0, eB2 = 0, sB2 = 0;
            int pA2 = lo + 2 * st + 4;
            if (pA2 < hi)     { int2 q2 = ep[pA2];     eA2 = q2.x; sA2 = q2.y; }
            if (pA2 + 1 < hi) { int2 r2 = ep[pA2 + 1]; eB2 = r2.x; sB2 = r2.y; }
            // ---- edge MLP (dual; b128 weights, b64 broadcast staging) ----
            sEa2[gid][k] = make_float2(eaAv, eaBv);
            float accA = peA, accB = peB;
            #pragma unroll
            for (int i4 = 0; i4 < 8; ++i4) {
                float4 w = w2p[i4];
                float2 v0 = sEa2[gid][4 * i4 + 0];
                float2 v1 = sEa2[gid][4 * i4 + 1];
                float2 v2 = sEa2[gid][4 * i4 + 2];
                float2 v3 = sEa2[gid][4 * i4 + 3];
                accA += v0.x * w.x + v1.x * w.y + v2.x * w.z + v3.x * w.w;
                accB += v0.y * w.x + v1.y * w.y + v2.y * w.z + v3.y * w.w;
            }
            float eoA = fmaxf(accA, 0.f), eoB = fmaxf(accB, 0.f);
            bool okB = (lo + 2 * st + 1) < hi;
            e_out[(long)eA * EO + k] = eoA;
            if (okB) e_out[(long)eB * EO + k] = eoB;
            sEo2[gid][k] = make_float2(eoA, eoB);
            // ---- h = xl + xr + eo@We (dual; b128 weights) ----
            float hA0 = xlA0 + xr0, hA1 = xlA1 + xr1, hA2 = xlA2 + xr2;
            float hB0 = xlB0 + xr0, hB1 = xlB1 + xr1, hB2 = xlB2 + xr2;
            #pragma unroll
            for (int i4 = 0; i4 < 8; ++i4) {
                float4 w0 = we0p[i4], w1 = we1p[i4], w2v = we2p[i4];
                float2 o0 = sEo2[gid][4 * i4 + 0];
                float2 o1 = sEo2[gid][4 * i4 + 1];
                float2 o2 = sEo2[gid][4 * i4 + 2];
                float2 o3 = sEo2[gid][4 * i4 + 3];
                hA0 += o0.x * w0.x + o1.x * w0.y + o2.x * w0.z + o3.x * w0.w;
                hA1 += o0.x * w1.x + o1.x * w1.y + o2.x * w1.z + o3.x * w1.w;
                hA2 += o0.x * w2v.x + o1.x * w2v.y + o2.x * w2v.z + o3.x * w2v.w;
                hB0 += o0.y * w0.x + o1.y * w0.y + o2.y * w0.z + o3.y * w0.w;
                hB1 += o0.y * w1.x + o1.y * w1.y + o2.y * w1.z + o3.y * w1.w;
                hB2 += o0.y * w2v.x + o1.y * w2v.y + o2.y * w2v.z + o3.y * w2v.w;
            }
            float pA0 = (hA0 > 0.f ? hA0 : NEG * hA0) * at0;
            float pA1 = (hA1 > 0.f ? hA1 : NEG * hA1) * at1;
            float pA2v = (hA2 > 0.f ? hA2 : NEG * hA2) * at2;
            float pB0 = (hB0 > 0.f ? hB0 : NEG * hB0) * at0;
            float pB1 = (hB1 > 0.f ? hB1 : NEG * hB1) * at1;
            float pB2 = (hB2 > 0.f ? hB2 : NEG * hB2) * at2;
            #pragma unroll
            for (int m = 1; m <= 16; m <<= 1) {
                pA0 += __shfl_xor(pA0, m, 32); pA1 += __shfl_xor(pA1, m, 32); pA2v += __shfl_xor(pA2v, m, 32);
                pB0 += __shfl_xor(pB0, m, 32); pB1 += __shfl_xor(pB1, m, 32); pB2 += __shfl_xor(pB2, m, 32);
            }
            float exA0 = __expf(pA0), exA1 = __expf(pA1), exA2 = __expf(pA2v);
            float exB0 = 0.f, exB1 = 0.f, exB2 = 0.f;
            if (okB) { exB0 = __expf(pB0); exB1 = __expf(pB1); exB2 = __expf(pB2); }
            a0 += exA0 * xlA0; a1 += exA1 * xlA1; a2 += exA2 * xlA2;
            a0 += exB0 * xlB0; a1 += exB1 * xlB1; a2 += exB2 * xlB2;
            d0 += exA0 + exB0; d1 += exA1 + exB1; d2 += exA2 + exB2;
            // rotate pipeline
            eA = eA1; sA = sA1; eB = eB1; sB = sB1;
            eA1 = eA2; sA1 = sA2; eB1 = eB2; sB1 = sB2;
            peA = peA_n; peB = peB_n; eaAv = eaA_n; eaBv = eaB_n;
            xlA0 = xlA0n; xlA1 = xlA1n; xlA2 = xlA2n;
            xlB0 = xlB0n; xlB1 = xlB1n; xlB2 = xlB2n;
        }
        g_out[n * HNO + k]      = (d0 > 0.f ? a0 / d0 : 0.f) + bg0;
        g_out[n * HNO + 32 + k] = (d1 > 0.f ? a1 / d1 : 0.f) + bg1;
        g_out[n * HNO + 64 + k] = (d2 > 0.f ? a2 / d2 : 0.f) + bg2;
    }
}

// ---------------- K2: x_new = relu([g, glob[batch]] @ W_n2 + b_n2) ----------------
__global__ __launch_bounds__(256) void k2_node_out(
    const float* __restrict__ g, const float* __restrict__ glob,
    const int* __restrict__ batch, const float* __restrict__ W_n2,
    const float* __restrict__ b_n2, float* __restrict__ x_new, int niters)
{
    __shared__ float sW[128 * 32];   // 16 KB
    __shared__ float sIn[8][128];    // 4 KB
    int t = threadIdx.x;
    for (int f = t; f < 128 * 32; f += 256) sW[f] = W_n2[f];
    __syncthreads();
    int k = t & 31, ni = t >> 5;
    float bn = b_n2[k];
    for (int it = 0; it < niters; ++it) {
        long n = ((long)blockIdx.x + (long)it * gridDim.x) * 8 + ni;
        long nc = (n < N_NODES) ? n : 0;
        #pragma unroll
        for (int r = 0; r < 3; ++r) {
            int j = r * 32 + k;
            sIn[ni][j] = g[nc * HNO + j];
        }
        sIn[ni][96 + k] = glob[(long)batch[nc] * GI + k];
        __syncthreads();
        float acc = bn;
        #pragma unroll 8
        for (int i = 0; i < 128; ++i) acc += sIn[ni][i] * sW[i * 32 + k];
        if (n < N_NODES) x_new[n * NO + k] = fmaxf(acc, 0.f);
        __syncthreads();
    }
}

// ---------------- K3: per-graph mean of x_new (batch sorted), then global MLP ----------------
__device__ __forceinline__ int lower_bound_dev(const int* __restrict__ a, int n, int v) {
    int lo = 0, hi = n;
    while (lo < hi) { int mid = (lo + hi) >> 1; if (a[mid] < v) lo = mid + 1; else hi = mid; }
    return lo;
}

__global__ __launch_bounds__(256) void k3_global(
    const float* __restrict__ x_new, const int* __restrict__ batch,
    const float* __restrict__ glob, const float* __restrict__ W_g,
    const float* __restrict__ b_g, float* __restrict__ u_new)
{
    __shared__ int s_lo, s_hi;
    __shared__ float s_part[8][32];
    __shared__ float s_mean[32];
    int g = blockIdx.x;
    if (threadIdx.x == 0) {
        s_lo = lower_bound_dev(batch, N_NODES, g);
        s_hi = lower_bound_dev(batch, N_NODES, g + 1);
    }
    __syncthreads();
    int lo = s_lo, hi = s_hi;
    int k = threadIdx.x & 31, c = threadIdx.x >> 5;
    float acc = 0.f;
    for (long n = lo + c; n < hi; n += 8) acc += x_new[n * NO + k];
    s_part[c][k] = acc;
    __syncthreads();
    if (threadIdx.x < 32) {
        float s = 0.f;
        #pragma unroll
        for (int c2 = 0; c2 < 8; ++c2) s += s_part[c2][k];
        int cnt = hi - lo;
        s_mean[k] = s / (float)(cnt > 0 ? cnt : 1);
    }
    __syncthreads();
    if (threadIdx.x < 32) {
        float acc2 = b_g[k];
        #pragma unroll
        for (int i = 0; i < 32; ++i) acc2 += glob[g * GI + i] * W_g[i * GO + k];
        #pragma unroll
        for (int i = 0; i < 32; ++i) acc2 += s_mean[i] * W_g[(32 + i) * GO + k];
        u_new[g * GO + k] = fmaxf(acc2, 0.f);
    }
}

extern "C" void kernel_launch(void* const* d_in, const int* in_sizes, int n_in,
                              void* d_out, int out_size, void* d_ws, size_t ws_size,
                              hipStream_t stream) {
    const float* x        = (const float*)d_in[0];
    const float* edge_attr= (const float*)d_in[1];
    const float* glob     = (const float*)d_in[2];
    const float* W_edge   = (const float*)d_in[3];
    const float* b_edge   = (const float*)d_in[4];
    const float* W_l      = (const float*)d_in[5];
    const float* b_l      = (const float*)d_in[6];
    const float* W_r      = (const float*)d_in[7];
    const float* b_r      = (const float*)d_in[8];
    const float* W_e      = (const float*)d_in[9];
    const float* att      = (const float*)d_in[10];
    const float* bias_gat = (const float*)d_in[11];
    const float* W_n2     = (const float*)d_in[12];
    const float* b_n2     = (const float*)d_in[13];
    const float* W_g      = (const float*)d_in[14];
    const float* b_g      = (const float*)d_in[15];
    const int* edge_index = (const int*)d_in[16];
    const int* batch      = (const int*)d_in[17];

    float* out   = (float*)d_out;
    float* x_new = out;                                    // N*32
    float* e_out = out + (size_t)N_NODES * NO;             // E*32
    float* u_new = e_out + (size_t)N_EDGES * EO;           // B*32

    // workspace layout (floats before ep sum to N*320 -> ep stays 8B-aligned)
    float*  ws    = (float*)d_ws;
    float*  xl    = ws;                                    // N*96
    float*  xr    = xl + (size_t)N_NODES * HNO;            // N*96
    float*  pre_e = xr + (size_t)N_NODES * HNO;            // N*32
    float*  g_buf = pre_e + (size_t)N_NODES * 32;          // N*96
    int2*   ep    = (int2*)(g_buf + (size_t)N_NODES * HNO);// E int2
    int*    cnt   = (int*)(ep + (size_t)N_EDGES);          // N
    int*    off   = cnt + N_NODES;                         // N+1
    int*    cursor= off + N_NODES + 1;                     // N
    int*    bsum  = cursor + N_NODES;                      // 128

    hipMemsetAsync(cnt, 0, (size_t)N_NODES * sizeof(int), stream);

    // CSR build (parallel scan)
    k_hist<<<1024, 256, 0, stream>>>(edge_index, cnt);
    k_scan1<<<SCAN_BLKS, 1024, 0, stream>>>(cnt, bsum);
    k_scan2<<<1, 128, 0, stream>>>(bsum);
    k_scan3<<<SCAN_BLKS, 1024, 0, stream>>>(cnt, bsum, off, cursor);
    k_scatter<<<1024, 256, 0, stream>>>(edge_index, cursor, ep);

    // node transforms (xl, xr, pre_e in one pass over x)
    int gridA = 1024;
    int groups64 = (N_NODES + 63) / 64;                    // 1563
    int itA = (groups64 + gridA - 1) / gridA;              // 2
    kA_node<<<gridA, 256, 0, stream>>>(x, W_l, b_l, W_r, b_r, W_edge, b_edge,
                                       xl, xr, pre_e, itA);

    // fused edge pass + aggregation (dual-edge, b128 weights)
    int gridF = 2048;
    int groups8 = (N_NODES + 7) / 8;                       // 12500
    int itF = (groups8 + gridF - 1) / gridF;               // 7
    kF<<<gridF, 256, 0, stream>>>(pre_e, edge_attr, W_edge, W_e, att, xl, xr,
                                  ep, off, bias_gat, e_out, g_buf, itF);

    // node_mlp_2
    int grid2 = 1024;
    int it2 = (groups8 + grid2 - 1) / grid2;               // 13
    k2_node_out<<<grid2, 256, 0, stream>>>(g_buf, glob, batch, W_n2, b_n2, x_new, it2);

    k3_global<<<NB, 256, 0, stream>>>(x_new, batch, glob, W_g, b_g, u_new);
}

// Round 10
// 1342.975 us; speedup vs baseline: 1.3686x; 1.0061x over previous
//
#include <hip/hip_runtime.h>

#define N_NODES 100000
#define N_EDGES 1600000
#define NB 64
#define NI 64
#define EI 32
#define GI 32
#define NO 32
#define EO 32
#define GO 32
#define HH 3
#define HNO 96   /* H*NO */
#define NEG 0.2f
#define SCAN_BLKS 98   /* ceil(100000/1024) */
#define SCAT_BLKS 1024
#define KE_BLKS 2048

// ---------------- KA: fused node transforms, register-blocked ----------------
__global__ __launch_bounds__(256) void kA_node(
    const float* __restrict__ x,
    const float* __restrict__ W_l, const float* __restrict__ b_l,
    const float* __restrict__ W_r, const float* __restrict__ b_r,
    const float* __restrict__ W_edge, const float* __restrict__ b_edge,
    float* __restrict__ xl, float* __restrict__ xr, float* __restrict__ pre_e,
    int niters)
{
    __shared__ float sWl[NI * HNO];   // 24 KB
    __shared__ float sWr[NI * HNO];   // 24 KB
    __shared__ float sWp[NI * 32];    // 8 KB  (W_edge rows 0..63)
    __shared__ float sx[64 * NI];     // 16 KB
    int t = threadIdx.x;
    for (int f = t; f < NI * HNO; f += 256) { sWl[f] = W_l[f]; sWr[f] = W_r[f]; }
    for (int f = t; f < NI * 32; f += 256) sWp[f] = W_edge[f];
    __syncthreads();
    int k = t & 31, g = t >> 5;
    float bl0 = b_l[k], bl1 = b_l[k + 32], bl2 = b_l[k + 64];
    float br0 = b_r[k], br1 = b_r[k + 32], br2 = b_r[k + 64];
    float bpe = b_edge[k];
    const long NX = (long)N_NODES * NI;
    for (int it = 0; it < niters; ++it) {
        long nb = ((long)blockIdx.x + (long)it * gridDim.x) * 64;
        long base = nb * NI;
        for (int f = t; f < 64 * NI; f += 256) {
            long idx = base + f;
            sx[f] = x[idx < NX ? idx : 0];
        }
        __syncthreads();
        float aL0[8], aL1[8], aL2[8], aR0[8], aR1[8], aR2[8], aP[8];
        #pragma unroll
        for (int m = 0; m < 8; ++m) {
            aL0[m] = bl0; aL1[m] = bl1; aL2[m] = bl2;
            aR0[m] = br0; aR1[m] = br1; aR2[m] = br2;
            aP[m] = bpe;
        }
        const float* sxg = &sx[g * 8 * NI];
        for (int i = 0; i < NI; ++i) {
            float wl0 = sWl[i * HNO + k], wl1 = sWl[i * HNO + 32 + k], wl2 = sWl[i * HNO + 64 + k];
            float wr0 = sWr[i * HNO + k], wr1 = sWr[i * HNO + 32 + k], wr2 = sWr[i * HNO + 64 + k];
            float wp  = sWp[i * 32 + k];
            #pragma unroll
            for (int m = 0; m < 8; ++m) {
                float xv = sxg[m * NI + i];
                aL0[m] += xv * wl0; aL1[m] += xv * wl1; aL2[m] += xv * wl2;
                aR0[m] += xv * wr0; aR1[m] += xv * wr1; aR2[m] += xv * wr2;
                aP[m]  += xv * wp;
            }
        }
        #pragma unroll
        for (int m = 0; m < 8; ++m) {
            long n = nb + g * 8 + m;
            if (n < N_NODES) {
                xl[n * HNO + k]      = aL0[m];
                xl[n * HNO + 32 + k] = aL1[m];
                xl[n * HNO + 64 + k] = aL2[m];
                xr[n * HNO + k]      = aR0[m];
                xr[n * HNO + 32 + k] = aR1[m];
                xr[n * HNO + 64 + k] = aR2[m];
                pre_e[n * 32 + k]    = aP[m];
            }
        }
        __syncthreads();
    }
}

// ---------------- K_hist: cnt[dst]++ ----------------
__global__ __launch_bounds__(256) void k_hist(const int* __restrict__ eidx, int* __restrict__ cnt)
{
    long i = (long)blockIdx.x * 256 + threadIdx.x;
    long stride = (long)gridDim.x * 256;
    for (; i < N_EDGES; i += stride)
        atomicAdd(&cnt[eidx[N_EDGES + i]], 1);
}

// ---------------- parallel scan: per-block sums ----------------
__global__ __launch_bounds__(1024) void k_scan1(const int* __restrict__ cnt, int* __restrict__ bsum)
{
    __shared__ int s[1024];
    int i = blockIdx.x * 1024 + threadIdx.x;
    s[threadIdx.x] = (i < N_NODES) ? cnt[i] : 0;
    for (int o = 512; o > 0; o >>= 1) {
        __syncthreads();
        if (threadIdx.x < o) s[threadIdx.x] += s[threadIdx.x + o];
    }
    if (threadIdx.x == 0) bsum[blockIdx.x] = s[0];
}

// ---------------- scan of the 98 block sums -> exclusive bases (in place) ----------------
__global__ __launch_bounds__(128) void k_scan2(int* __restrict__ bsum)
{
    __shared__ int s[128];
    int v = (threadIdx.x < SCAN_BLKS) ? bsum[threadIdx.x] : 0;
    s[threadIdx.x] = v;
    for (int o = 1; o < 128; o <<= 1) {
        __syncthreads();
        int a = (threadIdx.x >= o) ? s[threadIdx.x - o] : 0;
        __syncthreads();
        s[threadIdx.x] += a;
    }
    if (threadIdx.x < SCAN_BLKS) bsum[threadIdx.x] = s[threadIdx.x] - v;  // exclusive base
}

// ---------------- per-block rescan + write off/cursor ----------------
__global__ __launch_bounds__(1024) void k_scan3(const int* __restrict__ cnt,
                                                const int* __restrict__ bsum,
                                                int* __restrict__ off, int* __restrict__ cursor)
{
    __shared__ int s[1024];
    int i = blockIdx.x * 1024 + threadIdx.x;
    int v = (i < N_NODES) ? cnt[i] : 0;
    s[threadIdx.x] = v;
    for (int o = 1; o < 1024; o <<= 1) {
        __syncthreads();
        int a = (threadIdx.x >= o) ? s[threadIdx.x - o] : 0;
        __syncthreads();
        s[threadIdx.x] += a;
    }
    int excl = bsum[blockIdx.x] + s[threadIdx.x] - v;
    if (i < N_NODES) {
        off[i] = excl; cursor[i] = excl;
        if (i == N_NODES - 1) off[N_NODES] = excl + v;
    }
}

// ---------------- K_scat_ke: fused {CSR scatter} || {edge-ordered eo} ----------------
// Blocks [0, SCAT_BLKS): scatter {eid,src} pairs grouped by dst (needs cursor).
// Blocks [SCAT_BLKS, SCAT_BLKS+KE_BLKS): eo = relu(pre_e[src] + ea@W_edge[64:96,:])
//   written COALESCED to e_out (edge order). Independent work overlaps on the GPU.
__global__ __launch_bounds__(256) void k_scat_ke(
    const int* __restrict__ eidx, int* __restrict__ cursor, int2* __restrict__ ep,
    const float* __restrict__ pre_e, const float* __restrict__ ea,
    const float* __restrict__ W_edge, float* __restrict__ e_out)
{
    __shared__ float sW2[32 * 32];   // 4 KB  (W_edge rows 64..95)
    __shared__ float sEa[8][32];     // 1 KB  group-private staging
    int t = threadIdx.x;
    if (blockIdx.x < SCAT_BLKS) {
        long i = (long)blockIdx.x * 256 + t;
        long stride = (long)SCAT_BLKS * 256;
        for (; i < N_EDGES; i += stride) {
            int s = eidx[i];
            int d = eidx[N_EDGES + i];
            int pos = atomicAdd(&cursor[d], 1);
            ep[pos] = make_int2((int)i, s);
        }
    } else {
        int bid = blockIdx.x - SCAT_BLKS;
        for (int f = t; f < 32 * 32; f += 256) sW2[f] = W_edge[64 * 32 + f];
        __syncthreads();
        int k = t & 31, gid = t >> 5;
        const int niters = (N_EDGES + KE_BLKS * 8 - 1) / (KE_BLKS * 8);   // 98
        for (int it = 0; it < niters; ++it) {
            long e = ((long)bid + (long)it * KE_BLKS) * 8 + gid;
            bool valid = (e < N_EDGES);
            long ec = valid ? e : 0;
            int s = eidx[ec];
            float acc = pre_e[(long)s * 32 + k];
            sEa[gid][k] = ea[ec * EI + k];
            #pragma unroll 8
            for (int i = 0; i < 32; ++i) acc += sEa[gid][i] * sW2[i * 32 + k];
            if (valid) e_out[ec * EO + k] = fmaxf(acc, 0.f);
        }
    }
}

// ---------------- KF: dst-ordered attention pass, dual-edge (R7 loop, MLP removed) ----------------
// eo gathered from e_out (written by k_scat_ke). Per edge pair:
//   h_j = xl[src] + xr[dst] + eo @ W_e ; p_j = wave-reduce(lrelu(h)*att); ex = exp(p)
//   register aggregation a += ex*xl, d += ex. Tail writes g_out (node_mlp_2 in K2).
__global__ __launch_bounds__(256) void kF(
    const float* __restrict__ eo_in, const float* __restrict__ W_e,
    const float* __restrict__ att,
    const float* __restrict__ xl, const float* __restrict__ xr,
    const int2* __restrict__ ep, const int* __restrict__ off,
    const float* __restrict__ bias_gat,
    float* __restrict__ g_out, int niters)
{
    __shared__ float sWe[32 * 96];    // 12 KB
    __shared__ float2 sEo2[8][32];    // 2 KB dual staging (A,B)
    int t = threadIdx.x;
    for (int f = t; f < 32 * 96; f += 256) sWe[f] = W_e[f];
    __syncthreads();
    int k = t & 31, gid = t >> 5;
    float at0 = att[k], at1 = att[32 + k], at2 = att[64 + k];
    float bg0 = bias_gat[k], bg1 = bias_gat[32 + k], bg2 = bias_gat[64 + k];
    for (int it = 0; it < niters; ++it) {
        long n = ((long)blockIdx.x + (long)it * gridDim.x) * 8 + gid;
        if (n >= N_NODES) continue;
        int lo = off[n], hi = off[n + 1];
        float xr0 = xr[n * HNO + k];
        float xr1 = xr[n * HNO + 32 + k];
        float xr2 = xr[n * HNO + 64 + k];
        float a0 = 0.f, a1 = 0.f, a2 = 0.f;
        float d0 = 0.f, d1 = 0.f, d2 = 0.f;
        int deg = hi - lo;
        int steps = (deg + 1) >> 1;
        int eA = 0, sA = 0, eB = 0, sB = 0;
        int eA1 = 0, sA1 = 0, eB1 = 0, sB1 = 0;
        float eoAc = 0.f, eoBc = 0.f;
        float xlA0 = 0.f, xlA1 = 0.f, xlA2 = 0.f, xlB0 = 0.f, xlB1 = 0.f, xlB2 = 0.f;
        if (steps > 0) {
            int2 q = ep[lo]; eA = q.x; sA = q.y;
            if (lo + 1 < hi) { int2 r = ep[lo + 1]; eB = r.x; sB = r.y; }
            eoAc = eo_in[(long)eA * EO + k];
            eoBc = eo_in[(long)eB * EO + k];
            xlA0 = xl[(long)sA * HNO + k]; xlA1 = xl[(long)sA * HNO + 32 + k]; xlA2 = xl[(long)sA * HNO + 64 + k];
            xlB0 = xl[(long)sB * HNO + k]; xlB1 = xl[(long)sB * HNO + 32 + k]; xlB2 = xl[(long)sB * HNO + 64 + k];
            if (lo + 2 < hi) { int2 q1 = ep[lo + 2]; eA1 = q1.x; sA1 = q1.y; }
            if (lo + 3 < hi) { int2 r1 = ep[lo + 3]; eB1 = r1.x; sB1 = r1.y; }
        }
        for (int st = 0; st < steps; ++st) {
            // prefetch next-pair data (clamped-id defaults harmless)
            float eoA_n = eo_in[(long)eA1 * EO + k];
            float eoB_n = eo_in[(long)eB1 * EO + k];
            float xlA0n = xl[(long)sA1 * HNO + k], xlA1n = xl[(long)sA1 * HNO + 32 + k], xlA2n = xl[(long)sA1 * HNO + 64 + k];
            float xlB0n = xl[(long)sB1 * HNO + k], xlB1n = xl[(long)sB1 * HNO + 32 + k], xlB2n = xl[(long)sB1 * HNO + 64 + k];
            int eA2 = 0, sA2 = 0, eB2 = 0, sB2 = 0;
            int pA2 = lo + 2 * st + 4;
            if (pA2 < hi)     { int2 q2 = ep[pA2];     eA2 = q2.x; sA2 = q2.y; }
            if (pA2 + 1 < hi) { int2 r2 = ep[pA2 + 1]; eB2 = r2.x; sB2 = r2.y; }
            // ---- h = xl + xr + eo@We (dual) ----
            sEo2[gid][k] = make_float2(eoAc, eoBc);
            float hA0 = xlA0 + xr0, hA1 = xlA1 + xr1, hA2 = xlA2 + xr2;
            float hB0 = xlB0 + xr0, hB1 = xlB1 + xr1, hB2 = xlB2 + xr2;
            #pragma unroll 8
            for (int i = 0; i < 32; ++i) {
                float2 ov = sEo2[gid][i];
                float w0 = sWe[i * 96 + k], w1 = sWe[i * 96 + 32 + k], w2v = sWe[i * 96 + 64 + k];
                hA0 += ov.x * w0; hA1 += ov.x * w1; hA2 += ov.x * w2v;
                hB0 += ov.y * w0; hB1 += ov.y * w1; hB2 += ov.y * w2v;
            }
            float pA0 = (hA0 > 0.f ? hA0 : NEG * hA0) * at0;
            float pA1 = (hA1 > 0.f ? hA1 : NEG * hA1) * at1;
            float pA2v = (hA2 > 0.f ? hA2 : NEG * hA2) * at2;
            float pB0 = (hB0 > 0.f ? hB0 : NEG * hB0) * at0;
            float pB1 = (hB1 > 0.f ? hB1 : NEG * hB1) * at1;
            float pB2 = (hB2 > 0.f ? hB2 : NEG * hB2) * at2;
            #pragma unroll
            for (int m = 1; m <= 16; m <<= 1) {
                pA0 += __shfl_xor(pA0, m, 32); pA1 += __shfl_xor(pA1, m, 32); pA2v += __shfl_xor(pA2v, m, 32);
                pB0 += __shfl_xor(pB0, m, 32); pB1 += __shfl_xor(pB1, m, 32); pB2 += __shfl_xor(pB2, m, 32);
            }
            bool okB = (lo + 2 * st + 1) < hi;
            float exA0 = __expf(pA0), exA1 = __expf(pA1), exA2 = __expf(pA2v);
            float exB0 = 0.f, exB1 = 0.f, exB2 = 0.f;
            if (okB) { exB0 = __expf(pB0); exB1 = __expf(pB1); exB2 = __expf(pB2); }
            a0 += exA0 * xlA0; a1 += exA1 * xlA1; a2 += exA2 * xlA2;
            a0 += exB0 * xlB0; a1 += exB1 * xlB1; a2 += exB2 * xlB2;
            d0 += exA0 + exB0; d1 += exA1 + exB1; d2 += exA2 + exB2;
            // rotate pipeline
            eA = eA1; sA = sA1; eB = eB1; sB = sB1;
            eA1 = eA2; sA1 = sA2; eB1 = eB2; sB1 = sB2;
            eoAc = eoA_n; eoBc = eoB_n;
            xlA0 = xlA0n; xlA1 = xlA1n; xlA2 = xlA2n;
            xlB0 = xlB0n; xlB1 = xlB1n; xlB2 = xlB2n;
        }
        g_out[n * HNO + k]      = (d0 > 0.f ? a0 / d0 : 0.f) + bg0;
        g_out[n * HNO + 32 + k] = (d1 > 0.f ? a1 / d1 : 0.f) + bg1;
        g_out[n * HNO + 64 + k] = (d2 > 0.f ? a2 / d2 : 0.f) + bg2;
    }
}

// ---------------- K2: x_new = relu([g, glob[batch]] @ W_n2 + b_n2) ----------------
__global__ __launch_bounds__(256) void k2_node_out(
    const float* __restrict__ g, const float* __restrict__ glob,
    const int* __restrict__ batch, const float* __restrict__ W_n2,
    const float* __restrict__ b_n2, float* __restrict__ x_new, int niters)
{
    __shared__ float sW[128 * 32];   // 16 KB
    __shared__ float sIn[8][128];    // 4 KB
    int t = threadIdx.x;
    for (int f = t; f < 128 * 32; f += 256) sW[f] = W_n2[f];
    __syncthreads();
    int k = t & 31, ni = t >> 5;
    float bn = b_n2[k];
    for (int it = 0; it < niters; ++it) {
        long n = ((long)blockIdx.x + (long)it * gridDim.x) * 8 + ni;
        long nc = (n < N_NODES) ? n : 0;
        #pragma unroll
        for (int r = 0; r < 3; ++r) {
            int j = r * 32 + k;
            sIn[ni][j] = g[nc * HNO + j];
        }
        sIn[ni][96 + k] = glob[(long)batch[nc] * GI + k];
        __syncthreads();
        float acc = bn;
        #pragma unroll 8
        for (int i = 0; i < 128; ++i) acc += sIn[ni][i] * sW[i * 32 + k];
        if (n < N_NODES) x_new[n * NO + k] = fmaxf(acc, 0.f);
        __syncthreads();
    }
}

// ---------------- K3: per-graph mean of x_new (batch sorted), then global MLP ----------------
__device__ __forceinline__ int lower_bound_dev(const int* __restrict__ a, int n, int v) {
    int lo = 0, hi = n;
    while (lo < hi) { int mid = (lo + hi) >> 1; if (a[mid] < v) lo = mid + 1; else hi = mid; }
    return lo;
}

__global__ __launch_bounds__(256) void k3_global(
    const float* __restrict__ x_new, const int* __restrict__ batch,
    const float* __restrict__ glob, const float* __restrict__ W_g,
    const float* __restrict__ b_g, float* __restrict__ u_new)
{
    __shared__ int s_lo, s_hi;
    __shared__ float s_part[8][32];
    __shared__ float s_mean[32];
    int g = blockIdx.x;
    if (threadIdx.x == 0) {
        s_lo = lower_bound_dev(batch, N_NODES, g);
        s_hi = lower_bound_dev(batch, N_NODES, g + 1);
    }
    __syncthreads();
    int lo = s_lo, hi = s_hi;
    int k = threadIdx.x & 31, c = threadIdx.x >> 5;
    float acc = 0.f;
    for (long n = lo + c; n < hi; n += 8) acc += x_new[n * NO + k];
    s_part[c][k] = acc;
    __syncthreads();
    if (threadIdx.x < 32) {
        float s = 0.f;
        #pragma unroll
        for (int c2 = 0; c2 < 8; ++c2) s += s_part[c2][k];
        int cnt = hi - lo;
        s_mean[k] = s / (float)(cnt > 0 ? cnt : 1);
    }
    __syncthreads();
    if (threadIdx.x < 32) {
        float acc2 = b_g[k];
        #pragma unroll
        for (int i = 0; i < 32; ++i) acc2 += glob[g * GI + i] * W_g[i * GO + k];
        #pragma unroll
        for (int i = 0; i < 32; ++i) acc2 += s_mean[i] * W_g[(32 + i) * GO + k];
        u_new[g * GO + k] = fmaxf(acc2, 0.f);
    }
}

extern "C" void kernel_launch(void* const* d_in, const int* in_sizes, int n_in,
                              void* d_out, int out_size, void* d_ws, size_t ws_size,
                              hipStream_t stream) {
    const float* x        = (const float*)d_in[0];
    const float* edge_attr= (const float*)d_in[1];
    const float* glob     = (const float*)d_in[2];
    const float* W_edge   = (const float*)d_in[3];
    const float* b_edge   = (const float*)d_in[4];
    const float* W_l      = (const float*)d_in[5];
    const float* b_l      = (const float*)d_in[6];
    const float* W_r      = (const float*)d_in[7];
    const float* b_r      = (const float*)d_in[8];
    const float* W_e      = (const float*)d_in[9];
    const float* att      = (const float*)d_in[10];
    const float* bias_gat = (const float*)d_in[11];
    const float* W_n2     = (const float*)d_in[12];
    const float* b_n2     = (const float*)d_in[13];
    const float* W_g      = (const float*)d_in[14];
    const float* b_g      = (const float*)d_in[15];
    const int* edge_index = (const int*)d_in[16];
    const int* batch      = (const int*)d_in[17];

    float* out   = (float*)d_out;
    float* x_new = out;                                    // N*32
    float* e_out = out + (size_t)N_NODES * NO;             // E*32
    float* u_new = e_out + (size_t)N_EDGES * EO;           // B*32

    // workspace layout (floats before ep sum to N*320 -> ep stays 8B-aligned)
    float*  ws    = (float*)d_ws;
    float*  xl    = ws;                                    // N*96
    float*  xr    = xl + (size_t)N_NODES * HNO;            // N*96
    float*  pre_e = xr + (size_t)N_NODES * HNO;            // N*32
    float*  g_buf = pre_e + (size_t)N_NODES * 32;          // N*96
    int2*   ep    = (int2*)(g_buf + (size_t)N_NODES * HNO);// E int2
    int*    cnt   = (int*)(ep + (size_t)N_EDGES);          // N
    int*    off   = cnt + N_NODES;                         // N+1
    int*    cursor= off + N_NODES + 1;                     // N
    int*    bsum  = cursor + N_NODES;                      // 128

    hipMemsetAsync(cnt, 0, (size_t)N_NODES * sizeof(int), stream);

    // CSR build (parallel scan)
    k_hist<<<1024, 256, 0, stream>>>(edge_index, cnt);
    k_scan1<<<SCAN_BLKS, 1024, 0, stream>>>(cnt, bsum);
    k_scan2<<<1, 128, 0, stream>>>(bsum);
    k_scan3<<<SCAN_BLKS, 1024, 0, stream>>>(cnt, bsum, off, cursor);

    // node transforms (xl, xr, pre_e in one pass over x) — before fused scatter/kE
    int gridA = 1024;
    int groups64 = (N_NODES + 63) / 64;                    // 1563
    int itA = (groups64 + gridA - 1) / gridA;              // 2
    kA_node<<<gridA, 256, 0, stream>>>(x, W_l, b_l, W_r, b_r, W_edge, b_edge,
                                       xl, xr, pre_e, itA);

    // fused: CSR scatter || edge-ordered eo (coalesced e_out)
    k_scat_ke<<<SCAT_BLKS + KE_BLKS, 256, 0, stream>>>(edge_index, cursor, ep,
                                                       pre_e, edge_attr, W_edge, e_out);

    // attention pass + aggregation (dual-edge, eo gathered)
    int gridF = 2048;
    int groups8 = (N_NODES + 7) / 8;                       // 12500
    int itF = (groups8 + gridF - 1) / gridF;               // 7
    kF<<<gridF, 256, 0, stream>>>(e_out, W_e, att, xl, xr,
                                  ep, off, bias_gat, g_buf, itF);

    // node_mlp_2
    int grid2 = 1024;
    int it2 = (groups8 + grid2 - 1) / grid2;               // 13
    k2_node_out<<<grid2, 256, 0, stream>>>(g_buf, glob, batch, W_n2, b_n2, x_new, it2);

    k3_global<<<NB, 256, 0, stream>>>(x_new, batch, glob, W_g, b_g, u_new);
}

// Round 11
// 1285.693 us; speedup vs baseline: 1.4295x; 1.0446x over previous
//
#include <hip/hip_runtime.h>

#define N_NODES 100000
#define N_EDGES 1600000
#define NB 64
#define NI 64
#define EI 32
#define GI 32
#define NO 32
#define EO 32
#define GO 32
#define HH 3
#define HNO 96   /* H*NO */
#define NEG 0.2f
#define SCAN_BLKS 98   /* ceil(100000/1024) */

// ---------------- KA: fused node transforms, register-blocked ----------------
// xl/xr written INTERLEAVED: xl3[n*96 + k*3 + h]  (12B per lane per node, merged dwordx3)
__global__ __launch_bounds__(256) void kA_node(
    const float* __restrict__ x,
    const float* __restrict__ W_l, const float* __restrict__ b_l,
    const float* __restrict__ W_r, const float* __restrict__ b_r,
    const float* __restrict__ W_edge, const float* __restrict__ b_edge,
    float* __restrict__ xl3, float* __restrict__ xr3, float* __restrict__ pre_e,
    int niters)
{
    __shared__ float sWl[NI * HNO];   // 24 KB
    __shared__ float sWr[NI * HNO];   // 24 KB
    __shared__ float sWp[NI * 32];    // 8 KB  (W_edge rows 0..63)
    __shared__ float sx[64 * NI];     // 16 KB
    int t = threadIdx.x;
    for (int f = t; f < NI * HNO; f += 256) { sWl[f] = W_l[f]; sWr[f] = W_r[f]; }
    for (int f = t; f < NI * 32; f += 256) sWp[f] = W_edge[f];
    __syncthreads();
    int k = t & 31, g = t >> 5;
    float bl0 = b_l[k], bl1 = b_l[k + 32], bl2 = b_l[k + 64];
    float br0 = b_r[k], br1 = b_r[k + 32], br2 = b_r[k + 64];
    float bpe = b_edge[k];
    const long NX = (long)N_NODES * NI;
    for (int it = 0; it < niters; ++it) {
        long nb = ((long)blockIdx.x + (long)it * gridDim.x) * 64;
        long base = nb * NI;
        for (int f = t; f < 64 * NI; f += 256) {
            long idx = base + f;
            sx[f] = x[idx < NX ? idx : 0];
        }
        __syncthreads();
        float aL0[8], aL1[8], aL2[8], aR0[8], aR1[8], aR2[8], aP[8];
        #pragma unroll
        for (int m = 0; m < 8; ++m) {
            aL0[m] = bl0; aL1[m] = bl1; aL2[m] = bl2;
            aR0[m] = br0; aR1[m] = br1; aR2[m] = br2;
            aP[m] = bpe;
        }
        const float* sxg = &sx[g * 8 * NI];
        for (int i = 0; i < NI; ++i) {
            float wl0 = sWl[i * HNO + k], wl1 = sWl[i * HNO + 32 + k], wl2 = sWl[i * HNO + 64 + k];
            float wr0 = sWr[i * HNO + k], wr1 = sWr[i * HNO + 32 + k], wr2 = sWr[i * HNO + 64 + k];
            float wp  = sWp[i * 32 + k];
            #pragma unroll
            for (int m = 0; m < 8; ++m) {
                float xv = sxg[m * NI + i];
                aL0[m] += xv * wl0; aL1[m] += xv * wl1; aL2[m] += xv * wl2;
                aR0[m] += xv * wr0; aR1[m] += xv * wr1; aR2[m] += xv * wr2;
                aP[m]  += xv * wp;
            }
        }
        #pragma unroll
        for (int m = 0; m < 8; ++m) {
            long n = nb + g * 8 + m;
            if (n < N_NODES) {
                long b3 = n * HNO + (long)k * 3;
                xl3[b3]     = aL0[m];
                xl3[b3 + 1] = aL1[m];
                xl3[b3 + 2] = aL2[m];
                xr3[b3]     = aR0[m];
                xr3[b3 + 1] = aR1[m];
                xr3[b3 + 2] = aR2[m];
                pre_e[n * 32 + k] = aP[m];
            }
        }
        __syncthreads();
    }
}

// ---------------- K_hist: cnt[dst]++ ----------------
__global__ __launch_bounds__(256) void k_hist(const int* __restrict__ eidx, int* __restrict__ cnt)
{
    long i = (long)blockIdx.x * 256 + threadIdx.x;
    long stride = (long)gridDim.x * 256;
    for (; i < N_EDGES; i += stride)
        atomicAdd(&cnt[eidx[N_EDGES + i]], 1);
}

// ---------------- parallel scan: per-block sums ----------------
__global__ __launch_bounds__(1024) void k_scan1(const int* __restrict__ cnt, int* __restrict__ bsum)
{
    __shared__ int s[1024];
    int i = blockIdx.x * 1024 + threadIdx.x;
    s[threadIdx.x] = (i < N_NODES) ? cnt[i] : 0;
    for (int o = 512; o > 0; o >>= 1) {
        __syncthreads();
        if (threadIdx.x < o) s[threadIdx.x] += s[threadIdx.x + o];
    }
    if (threadIdx.x == 0) bsum[blockIdx.x] = s[0];
}

// ---------------- scan of the 98 block sums -> exclusive bases (in place) ----------------
__global__ __launch_bounds__(128) void k_scan2(int* __restrict__ bsum)
{
    __shared__ int s[128];
    int v = (threadIdx.x < SCAN_BLKS) ? bsum[threadIdx.x] : 0;
    s[threadIdx.x] = v;
    for (int o = 1; o < 128; o <<= 1) {
        __syncthreads();
        int a = (threadIdx.x >= o) ? s[threadIdx.x - o] : 0;
        __syncthreads();
        s[threadIdx.x] += a;
    }
    if (threadIdx.x < SCAN_BLKS) bsum[threadIdx.x] = s[threadIdx.x] - v;  // exclusive base
}

// ---------------- per-block rescan + write off/cursor ----------------
__global__ __launch_bounds__(1024) void k_scan3(const int* __restrict__ cnt,
                                                const int* __restrict__ bsum,
                                                int* __restrict__ off, int* __restrict__ cursor)
{
    __shared__ int s[1024];
    int i = blockIdx.x * 1024 + threadIdx.x;
    int v = (i < N_NODES) ? cnt[i] : 0;
    s[threadIdx.x] = v;
    for (int o = 1; o < 1024; o <<= 1) {
        __syncthreads();
        int a = (threadIdx.x >= o) ? s[threadIdx.x - o] : 0;
        __syncthreads();
        s[threadIdx.x] += a;
    }
    int excl = bsum[blockIdx.x] + s[threadIdx.x] - v;
    if (i < N_NODES) {
        off[i] = excl; cursor[i] = excl;
        if (i == N_NODES - 1) off[N_NODES] = excl + v;
    }
}

// ---------------- K_scatter: CSR {eid, src} pairs grouped by dst ----------------
__global__ __launch_bounds__(256) void k_scatter(const int* __restrict__ eidx,
                                                 int* __restrict__ cursor,
                                                 int2* __restrict__ ep)
{
    long i = (long)blockIdx.x * 256 + threadIdx.x;
    long stride = (long)gridDim.x * 256;
    for (; i < N_EDGES; i += stride) {
        int s = eidx[i];
        int d = eidx[N_EDGES + i];
        int pos = atomicAdd(&cursor[d], 1);
        ep[pos] = make_int2((int)i, s);
    }
}

// ---------------- KE: edge-ordered edge-MLP, dual-edge ----------------
// eo = relu(pre_e[src] + ea @ W_edge[64:96,:])  written coalesced to e_out.
// Each 32-lane group processes 2 consecutive edges; sW2 reads shared across both.
__global__ __launch_bounds__(256) void kE_edge(
    const int* __restrict__ eidx, const float* __restrict__ pre_e,
    const float* __restrict__ ea, const float* __restrict__ W_edge,
    float* __restrict__ e_out, int niters)
{
    __shared__ float sW2[32 * 32];    // 4 KB  (W_edge rows 64..95)
    __shared__ float2 sEa2[8][32];    // 2 KB
    int t = threadIdx.x;
    for (int f = t; f < 32 * 32; f += 256) sW2[f] = W_edge[64 * 32 + f];
    __syncthreads();
    int k = t & 31, gid = t >> 5;
    for (int it = 0; it < niters; ++it) {
        long e0 = ((long)blockIdx.x + (long)it * gridDim.x) * 16 + gid * 2;
        long e1 = e0 + 1;
        bool v0 = (e0 < N_EDGES), v1 = (e1 < N_EDGES);
        long c0 = v0 ? e0 : 0, c1 = v1 ? e1 : 0;
        int s0 = eidx[c0], s1 = eidx[c1];
        float acc0 = pre_e[(long)s0 * 32 + k];
        float acc1 = pre_e[(long)s1 * 32 + k];
        sEa2[gid][k] = make_float2(ea[c0 * EI + k], ea[c1 * EI + k]);
        #pragma unroll 8
        for (int i = 0; i < 32; ++i) {
            float w = sW2[i * 32 + k];
            float2 v = sEa2[gid][i];
            acc0 += v.x * w; acc1 += v.y * w;
        }
        if (v0) e_out[c0 * EO + k] = fmaxf(acc0, 0.f);
        if (v1) e_out[c1 * EO + k] = fmaxf(acc1, 0.f);
    }
}

// ---------------- KF: dst-ordered attention pass, dual-edge ----------------
// R10 loop with two layout micro-opts (register-neutral issue reduction):
//  - sWe interleaved [i][k*3+h]: lane k's 3 head weights = 12 adjacent B -> 1 ds_read_b96
//  - xl read from interleaved xl3 [n][k][h]: 1 merged 12B load/edge (was 3 strided)
__global__ __launch_bounds__(256) void kF(
    const float* __restrict__ eo_in, const float* __restrict__ W_e,
    const float* __restrict__ att,
    const float* __restrict__ xl3, const float* __restrict__ xr3,
    const int2* __restrict__ ep, const int* __restrict__ off,
    const float* __restrict__ bias_gat,
    float* __restrict__ g_out, int niters)
{
    __shared__ float sWeI[32 * 96];   // 12 KB  [i][k*3+h] = W_e[i*96 + h*32 + k]
    __shared__ float2 sEo2[8][32];    // 2 KB dual staging (A,B)
    int t = threadIdx.x;
    for (int f = t; f < 32 * 96; f += 256) {
        int i = f / 96, r = f - i * 96;
        int kk = r / 3, h = r - kk * 3;
        sWeI[f] = W_e[i * 96 + h * 32 + kk];
    }
    __syncthreads();
    int k = t & 31, gid = t >> 5;
    float at0 = att[k], at1 = att[32 + k], at2 = att[64 + k];
    float bg0 = bias_gat[k], bg1 = bias_gat[32 + k], bg2 = bias_gat[64 + k];
    const int k3 = k * 3;
    for (int it = 0; it < niters; ++it) {
        long n = ((long)blockIdx.x + (long)it * gridDim.x) * 8 + gid;
        if (n >= N_NODES) continue;
        int lo = off[n], hi = off[n + 1];
        long nb3 = n * HNO + k3;
        float xr0 = xr3[nb3], xr1 = xr3[nb3 + 1], xr2 = xr3[nb3 + 2];
        float a0 = 0.f, a1 = 0.f, a2 = 0.f;
        float d0 = 0.f, d1 = 0.f, d2 = 0.f;
        int deg = hi - lo;
        int steps = (deg + 1) >> 1;
        int eA = 0, sA = 0, eB = 0, sB = 0;
        int eA1 = 0, sA1 = 0, eB1 = 0, sB1 = 0;
        float eoAc = 0.f, eoBc = 0.f;
        float xlA0 = 0.f, xlA1 = 0.f, xlA2 = 0.f, xlB0 = 0.f, xlB1 = 0.f, xlB2 = 0.f;
        if (steps > 0) {
            int2 q = ep[lo]; eA = q.x; sA = q.y;
            if (lo + 1 < hi) { int2 r = ep[lo + 1]; eB = r.x; sB = r.y; }
            eoAc = eo_in[(long)eA * EO + k];
            eoBc = eo_in[(long)eB * EO + k];
            long a3 = (long)sA * HNO + k3, b3 = (long)sB * HNO + k3;
            xlA0 = xl3[a3]; xlA1 = xl3[a3 + 1]; xlA2 = xl3[a3 + 2];
            xlB0 = xl3[b3]; xlB1 = xl3[b3 + 1]; xlB2 = xl3[b3 + 2];
            if (lo + 2 < hi) { int2 q1 = ep[lo + 2]; eA1 = q1.x; sA1 = q1.y; }
            if (lo + 3 < hi) { int2 r1 = ep[lo + 3]; eB1 = r1.x; sB1 = r1.y; }
        }
        for (int st = 0; st < steps; ++st) {
            // prefetch next-pair data (clamped-id defaults harmless)
            float eoA_n = eo_in[(long)eA1 * EO + k];
            float eoB_n = eo_in[(long)eB1 * EO + k];
            long a3 = (long)sA1 * HNO + k3, b3 = (long)sB1 * HNO + k3;
            float xlA0n = xl3[a3], xlA1n = xl3[a3 + 1], xlA2n = xl3[a3 + 2];
            float xlB0n = xl3[b3], xlB1n = xl3[b3 + 1], xlB2n = xl3[b3 + 2];
            int eA2 = 0, sA2 = 0, eB2 = 0, sB2 = 0;
            int pA2 = lo + 2 * st + 4;
            if (pA2 < hi)     { int2 q2 = ep[pA2];     eA2 = q2.x; sA2 = q2.y; }
            if (pA2 + 1 < hi) { int2 r2 = ep[pA2 + 1]; eB2 = r2.x; sB2 = r2.y; }
            // ---- h = xl + xr + eo@We (dual; b96 weight reads) ----
            sEo2[gid][k] = make_float2(eoAc, eoBc);
            float hA0 = xlA0 + xr0, hA1 = xlA1 + xr1, hA2 = xlA2 + xr2;
            float hB0 = xlB0 + xr0, hB1 = xlB1 + xr1, hB2 = xlB2 + xr2;
            #pragma unroll 8
            for (int i = 0; i < 32; ++i) {
                float2 ov = sEo2[gid][i];
                const float* wp = &sWeI[i * 96 + k3];
                float w0 = wp[0], w1 = wp[1], w2v = wp[2];
                hA0 += ov.x * w0; hA1 += ov.x * w1; hA2 += ov.x * w2v;
                hB0 += ov.y * w0; hB1 += ov.y * w1; hB2 += ov.y * w2v;
            }
            float pA0 = (hA0 > 0.f ? hA0 : NEG * hA0) * at0;
            float pA1 = (hA1 > 0.f ? hA1 : NEG * hA1) * at1;
            float pA2v = (hA2 > 0.f ? hA2 : NEG * hA2) * at2;
            float pB0 = (hB0 > 0.f ? hB0 : NEG * hB0) * at0;
            float pB1 = (hB1 > 0.f ? hB1 : NEG * hB1) * at1;
            float pB2 = (hB2 > 0.f ? hB2 : NEG * hB2) * at2;
            #pragma unroll
            for (int m = 1; m <= 16; m <<= 1) {
                pA0 += __shfl_xor(pA0, m, 32); pA1 += __shfl_xor(pA1, m, 32); pA2v += __shfl_xor(pA2v, m, 32);
                pB0 += __shfl_xor(pB0, m, 32); pB1 += __shfl_xor(pB1, m, 32); pB2 += __shfl_xor(pB2, m, 32);
            }
            bool okB = (lo + 2 * st + 1) < hi;
            float exA0 = __expf(pA0), exA1 = __expf(pA1), exA2 = __expf(pA2v);
            float exB0 = 0.f, exB1 = 0.f, exB2 = 0.f;
            if (okB) { exB0 = __expf(pB0); exB1 = __expf(pB1); exB2 = __expf(pB2); }
            a0 += exA0 * xlA0; a1 += exA1 * xlA1; a2 += exA2 * xlA2;
            a0 += exB0 * xlB0; a1 += exB1 * xlB1; a2 += exB2 * xlB2;
            d0 += exA0 + exB0; d1 += exA1 + exB1; d2 += exA2 + exB2;
            // rotate pipeline
            eA = eA1; sA = sA1; eB = eB1; sB = sB1;
            eA1 = eA2; sA1 = sA2; eB1 = eB2; sB1 = sB2;
            eoAc = eoA_n; eoBc = eoB_n;
            xlA0 = xlA0n; xlA1 = xlA1n; xlA2 = xlA2n;
            xlB0 = xlB0n; xlB1 = xlB1n; xlB2 = xlB2n;
        }
        g_out[n * HNO + k]      = (d0 > 0.f ? a0 / d0 : 0.f) + bg0;
        g_out[n * HNO + 32 + k] = (d1 > 0.f ? a1 / d1 : 0.f) + bg1;
        g_out[n * HNO + 64 + k] = (d2 > 0.f ? a2 / d2 : 0.f) + bg2;
    }
}

// ---------------- K2: x_new = relu([g, glob[batch]] @ W_n2 + b_n2) ----------------
__global__ __launch_bounds__(256) void k2_node_out(
    const float* __restrict__ g, const float* __restrict__ glob,
    const int* __restrict__ batch, const float* __restrict__ W_n2,
    const float* __restrict__ b_n2, float* __restrict__ x_new, int niters)
{
    __shared__ float sW[128 * 32];   // 16 KB
    __shared__ float sIn[8][128];    // 4 KB
    int t = threadIdx.x;
    for (int f = t; f < 128 * 32; f += 256) sW[f] = W_n2[f];
    __syncthreads();
    int k = t & 31, ni = t >> 5;
    float bn = b_n2[k];
    for (int it = 0; it < niters; ++it) {
        long n = ((long)blockIdx.x + (long)it * gridDim.x) * 8 + ni;
        long nc = (n < N_NODES) ? n : 0;
        #pragma unroll
        for (int r = 0; r < 3; ++r) {
            int j = r * 32 + k;
            sIn[ni][j] = g[nc * HNO + j];
        }
        sIn[ni][96 + k] = glob[(long)batch[nc] * GI + k];
        __syncthreads();
        float acc = bn;
        #pragma unroll 8
        for (int i = 0; i < 128; ++i) acc += sIn[ni][i] * sW[i * 32 + k];
        if (n < N_NODES) x_new[n * NO + k] = fmaxf(acc, 0.f);
        __syncthreads();
    }
}

// ---------------- K3: per-graph mean of x_new (batch sorted), then global MLP ----------------
__device__ __forceinline__ int lower_bound_dev(const int* __restrict__ a, int n, int v) {
    int lo = 0, hi = n;
    while (lo < hi) { int mid = (lo + hi) >> 1; if (a[mid] < v) lo = mid + 1; else hi = mid; }
    return lo;
}

__global__ __launch_bounds__(256) void k3_global(
    const float* __restrict__ x_new, const int* __restrict__ batch,
    const float* __restrict__ glob, const float* __restrict__ W_g,
    const float* __restrict__ b_g, float* __restrict__ u_new)
{
    __shared__ int s_lo, s_hi;
    __shared__ float s_part[8][32];
    __shared__ float s_mean[32];
    int g = blockIdx.x;
    if (threadIdx.x == 0) {
        s_lo = lower_bound_dev(batch, N_NODES, g);
        s_hi = lower_bound_dev(batch, N_NODES, g + 1);
    }
    __syncthreads();
    int lo = s_lo, hi = s_hi;
    int k = threadIdx.x & 31, c = threadIdx.x >> 5;
    float acc = 0.f;
    for (long n = lo + c; n < hi; n += 8) acc += x_new[n * NO + k];
    s_part[c][k] = acc;
    __syncthreads();
    if (threadIdx.x < 32) {
        float s = 0.f;
        #pragma unroll
        for (int c2 = 0; c2 < 8; ++c2) s += s_part[c2][k];
        int cnt = hi - lo;
        s_mean[k] = s / (float)(cnt > 0 ? cnt : 1);
    }
    __syncthreads();
    if (threadIdx.x < 32) {
        float acc2 = b_g[k];
        #pragma unroll
        for (int i = 0; i < 32; ++i) acc2 += glob[g * GI + i] * W_g[i * GO + k];
        #pragma unroll
        for (int i = 0; i < 32; ++i) acc2 += s_mean[i] * W_g[(32 + i) * GO + k];
        u_new[g * GO + k] = fmaxf(acc2, 0.f);
    }
}

extern "C" void kernel_launch(void* const* d_in, const int* in_sizes, int n_in,
                              void* d_out, int out_size, void* d_ws, size_t ws_size,
                              hipStream_t stream) {
    const float* x        = (const float*)d_in[0];
    const float* edge_attr= (const float*)d_in[1];
    const float* glob     = (const float*)d_in[2];
    const float* W_edge   = (const float*)d_in[3];
    const float* b_edge   = (const float*)d_in[4];
    const float* W_l      = (const float*)d_in[5];
    const float* b_l      = (const float*)d_in[6];
    const float* W_r      = (const float*)d_in[7];
    const float* b_r      = (const float*)d_in[8];
    const float* W_e      = (const float*)d_in[9];
    const float* att      = (const float*)d_in[10];
    const float* bias_gat = (const float*)d_in[11];
    const float* W_n2     = (const float*)d_in[12];
    const float* b_n2     = (const float*)d_in[13];
    const float* W_g      = (const float*)d_in[14];
    const float* b_g      = (const float*)d_in[15];
    const int* edge_index = (const int*)d_in[16];
    const int* batch      = (const int*)d_in[17];

    float* out   = (float*)d_out;
    float* x_new = out;                                    // N*32
    float* e_out = out + (size_t)N_NODES * NO;             // E*32
    float* u_new = e_out + (size_t)N_EDGES * EO;           // B*32

    // workspace layout (floats before ep sum to N*320 -> ep stays 8B-aligned)
    float*  ws    = (float*)d_ws;
    float*  xl3   = ws;                                    // N*96 (interleaved)
    float*  xr3   = xl3 + (size_t)N_NODES * HNO;           // N*96 (interleaved)
    float*  pre_e = xr3 + (size_t)N_NODES * HNO;           // N*32
    float*  g_buf = pre_e + (size_t)N_NODES * 32;          // N*96
    int2*   ep    = (int2*)(g_buf + (size_t)N_NODES * HNO);// E int2
    int*    cnt   = (int*)(ep + (size_t)N_EDGES);          // N
    int*    off   = cnt + N_NODES;                         // N+1
    int*    cursor= off + N_NODES + 1;                     // N
    int*    bsum  = cursor + N_NODES;                      // 128

    hipMemsetAsync(cnt, 0, (size_t)N_NODES * sizeof(int), stream);

    // CSR build (parallel scan)
    k_hist<<<1024, 256, 0, stream>>>(edge_index, cnt);
    k_scan1<<<SCAN_BLKS, 1024, 0, stream>>>(cnt, bsum);
    k_scan2<<<1, 128, 0, stream>>>(bsum);
    k_scan3<<<SCAN_BLKS, 1024, 0, stream>>>(cnt, bsum, off, cursor);
    k_scatter<<<1024, 256, 0, stream>>>(edge_index, cursor, ep);

    // node transforms (xl3, xr3, pre_e in one pass over x)
    int gridA = 1024;
    int groups64 = (N_NODES + 63) / 64;                    // 1563
    int itA = (groups64 + gridA - 1) / gridA;              // 2
    kA_node<<<gridA, 256, 0, stream>>>(x, W_l, b_l, W_r, b_r, W_edge, b_edge,
                                       xl3, xr3, pre_e, itA);

    // edge MLP (edge-ordered, coalesced e_out)
    int gridE = 2048;
    int groupsE = (N_EDGES + 15) / 16;                     // 100000
    int itE = (groupsE + gridE - 1) / gridE;               // 49
    kE_edge<<<gridE, 256, 0, stream>>>(edge_index, pre_e, edge_attr, W_edge, e_out, itE);

    // attention pass + aggregation (dual-edge)
    int gridF = 2048;
    int groups8 = (N_NODES + 7) / 8;                       // 12500
    int itF = (groups8 + gridF - 1) / gridF;               // 7
    kF<<<gridF, 256, 0, stream>>>(e_out, W_e, att, xl3, xr3,
                                  ep, off, bias_gat, g_buf, itF);

    // node_mlp_2
    int grid2 = 1024;
    int it2 = (groups8 + grid2 - 1) / grid2;               // 13
    k2_node_out<<<grid2, 256, 0, stream>>>(g_buf, glob, batch, W_n2, b_n2, x_new, it2);

    k3_global<<<NB, 256, 0, stream>>>(x_new, batch, glob, W_g, b_g, u_new);
}

// Round 12
// 1254.969 us; speedup vs baseline: 1.4645x; 1.0245x over previous
//
#include <hip/hip_runtime.h>

#define N_NODES 100000
#define N_EDGES 1600000
#define NB 64
#define NI 64
#define EI 32
#define GI 32
#define NO 32
#define EO 32
#define GO 32
#define HH 3
#define HNO 96   /* H*NO */
#define NEG 0.2f
#define SCAN_BLKS 98   /* ceil(100000/1024) */

// ---------------- KA: fused node transforms + dst histogram ----------------
// Histogram atomics issued first (fire-and-forget); their latency hides under the
// register-blocked transform compute. xl/xr written INTERLEAVED: xl3[n*96 + k*3 + h].
__global__ __launch_bounds__(256) void kA_node(
    const float* __restrict__ x, const int* __restrict__ eidx, int* __restrict__ cnt,
    const float* __restrict__ W_l, const float* __restrict__ b_l,
    const float* __restrict__ W_r, const float* __restrict__ b_r,
    const float* __restrict__ W_edge, const float* __restrict__ b_edge,
    float* __restrict__ xl3, float* __restrict__ xr3, float* __restrict__ pre_e,
    int niters)
{
    __shared__ float sWl[NI * HNO];   // 24 KB
    __shared__ float sWr[NI * HNO];   // 24 KB
    __shared__ float sWp[NI * 32];    // 8 KB  (W_edge rows 0..63)
    __shared__ float sx[64 * NI];     // 16 KB
    int t = threadIdx.x;
    // --- dst histogram (independent; overlaps with everything below) ---
    {
        long i = (long)blockIdx.x * 256 + t;
        long stride = (long)gridDim.x * 256;
        for (; i < N_EDGES; i += stride)
            atomicAdd(&cnt[eidx[N_EDGES + i]], 1);
    }
    for (int f = t; f < NI * HNO; f += 256) { sWl[f] = W_l[f]; sWr[f] = W_r[f]; }
    for (int f = t; f < NI * 32; f += 256) sWp[f] = W_edge[f];
    __syncthreads();
    int k = t & 31, g = t >> 5;
    float bl0 = b_l[k], bl1 = b_l[k + 32], bl2 = b_l[k + 64];
    float br0 = b_r[k], br1 = b_r[k + 32], br2 = b_r[k + 64];
    float bpe = b_edge[k];
    const long NX = (long)N_NODES * NI;
    for (int it = 0; it < niters; ++it) {
        long nb = ((long)blockIdx.x + (long)it * gridDim.x) * 64;
        long base = nb * NI;
        for (int f = t; f < 64 * NI; f += 256) {
            long idx = base + f;
            sx[f] = x[idx < NX ? idx : 0];
        }
        __syncthreads();
        float aL0[8], aL1[8], aL2[8], aR0[8], aR1[8], aR2[8], aP[8];
        #pragma unroll
        for (int m = 0; m < 8; ++m) {
            aL0[m] = bl0; aL1[m] = bl1; aL2[m] = bl2;
            aR0[m] = br0; aR1[m] = br1; aR2[m] = br2;
            aP[m] = bpe;
        }
        const float* sxg = &sx[g * 8 * NI];
        for (int i = 0; i < NI; ++i) {
            float wl0 = sWl[i * HNO + k], wl1 = sWl[i * HNO + 32 + k], wl2 = sWl[i * HNO + 64 + k];
            float wr0 = sWr[i * HNO + k], wr1 = sWr[i * HNO + 32 + k], wr2 = sWr[i * HNO + 64 + k];
            float wp  = sWp[i * 32 + k];
            #pragma unroll
            for (int m = 0; m < 8; ++m) {
                float xv = sxg[m * NI + i];
                aL0[m] += xv * wl0; aL1[m] += xv * wl1; aL2[m] += xv * wl2;
                aR0[m] += xv * wr0; aR1[m] += xv * wr1; aR2[m] += xv * wr2;
                aP[m]  += xv * wp;
            }
        }
        #pragma unroll
        for (int m = 0; m < 8; ++m) {
            long n = nb + g * 8 + m;
            if (n < N_NODES) {
                long b3 = n * HNO + (long)k * 3;
                xl3[b3]     = aL0[m];
                xl3[b3 + 1] = aL1[m];
                xl3[b3 + 2] = aL2[m];
                xr3[b3]     = aR0[m];
                xr3[b3 + 1] = aR1[m];
                xr3[b3 + 2] = aR2[m];
                pre_e[n * 32 + k] = aP[m];
            }
        }
        __syncthreads();
    }
}

// ---------------- parallel scan: per-block sums ----------------
__global__ __launch_bounds__(1024) void k_scan1(const int* __restrict__ cnt, int* __restrict__ bsum)
{
    __shared__ int s[1024];
    int i = blockIdx.x * 1024 + threadIdx.x;
    s[threadIdx.x] = (i < N_NODES) ? cnt[i] : 0;
    for (int o = 512; o > 0; o >>= 1) {
        __syncthreads();
        if (threadIdx.x < o) s[threadIdx.x] += s[threadIdx.x + o];
    }
    if (threadIdx.x == 0) bsum[blockIdx.x] = s[0];
}

// ---------------- scan of the 98 block sums -> exclusive bases (in place) ----------------
__global__ __launch_bounds__(128) void k_scan2(int* __restrict__ bsum)
{
    __shared__ int s[128];
    int v = (threadIdx.x < SCAN_BLKS) ? bsum[threadIdx.x] : 0;
    s[threadIdx.x] = v;
    for (int o = 1; o < 128; o <<= 1) {
        __syncthreads();
        int a = (threadIdx.x >= o) ? s[threadIdx.x - o] : 0;
        __syncthreads();
        s[threadIdx.x] += a;
    }
    if (threadIdx.x < SCAN_BLKS) bsum[threadIdx.x] = s[threadIdx.x] - v;  // exclusive base
}

// ---------------- per-block rescan + write off/cursor ----------------
__global__ __launch_bounds__(1024) void k_scan3(const int* __restrict__ cnt,
                                                const int* __restrict__ bsum,
                                                int* __restrict__ off, int* __restrict__ cursor)
{
    __shared__ int s[1024];
    int i = blockIdx.x * 1024 + threadIdx.x;
    int v = (i < N_NODES) ? cnt[i] : 0;
    s[threadIdx.x] = v;
    for (int o = 1; o < 1024; o <<= 1) {
        __syncthreads();
        int a = (threadIdx.x >= o) ? s[threadIdx.x - o] : 0;
        __syncthreads();
        s[threadIdx.x] += a;
    }
    int excl = bsum[blockIdx.x] + s[threadIdx.x] - v;
    if (i < N_NODES) {
        off[i] = excl; cursor[i] = excl;
        if (i == N_NODES - 1) off[N_NODES] = excl + v;
    }
}

// ---------------- KEscat: edge-ordered edge-MLP (dual) + fused CSR scatter ----------------
// All 32 lanes: eo = relu(pre_e[src] + ea @ W_edge[64:96,:]) -> e_out (coalesced).
// Lanes 0/1 additionally scatter {eid,src} into ep via cursor atomic; the dependent
// atomic->store chain hides under the 32-iteration MLP loop.
__global__ __launch_bounds__(256) void kEscat(
    const int* __restrict__ eidx, int* __restrict__ cursor, int2* __restrict__ ep,
    const float* __restrict__ pre_e, const float* __restrict__ ea,
    const float* __restrict__ W_edge, float* __restrict__ e_out, int niters)
{
    __shared__ float sW2[32 * 32];    // 4 KB  (W_edge rows 64..95)
    __shared__ float2 sEa2[8][32];    // 2 KB
    int t = threadIdx.x;
    for (int f = t; f < 32 * 32; f += 256) sW2[f] = W_edge[64 * 32 + f];
    __syncthreads();
    int k = t & 31, gid = t >> 5;
    for (int it = 0; it < niters; ++it) {
        long e0 = ((long)blockIdx.x + (long)it * gridDim.x) * 16 + gid * 2;
        long e1 = e0 + 1;
        bool v0 = (e0 < N_EDGES), v1 = (e1 < N_EDGES);
        long c0 = v0 ? e0 : 0, c1 = v1 ? e1 : 0;
        int s0 = eidx[c0], s1 = eidx[c1];
        // scatter (lanes 0/1), overlapped with the MLP below
        if (k < 2) {
            bool vv = (k == 0) ? v0 : v1;
            if (vv) {
                long ce = (k == 0) ? c0 : c1;
                int ss = (k == 0) ? s0 : s1;
                int dd = eidx[N_EDGES + ce];
                int pos = atomicAdd(&cursor[dd], 1);
                ep[pos] = make_int2((int)ce, ss);
            }
        }
        float acc0 = pre_e[(long)s0 * 32 + k];
        float acc1 = pre_e[(long)s1 * 32 + k];
        sEa2[gid][k] = make_float2(ea[c0 * EI + k], ea[c1 * EI + k]);
        #pragma unroll 8
        for (int i = 0; i < 32; ++i) {
            float w = sW2[i * 32 + k];
            float2 v = sEa2[gid][i];
            acc0 += v.x * w; acc1 += v.y * w;
        }
        if (v0) e_out[c0 * EO + k] = fmaxf(acc0, 0.f);
        if (v1) e_out[c1 * EO + k] = fmaxf(acc1, 0.f);
    }
}

// ---------------- KF: dst-ordered attention pass, dual-edge, fused node_mlp_2 tail ----------------
// Per edge pair: h = xl[src]+xr[dst]+eo@We; p = wave-reduce(lrelu(h)*att); ex = exp(p);
// register aggregation. Tail: g = a/d + bias_gat; x_new = relu([g, glob[batch]]@W_n2 + b_n2).
__global__ __launch_bounds__(256) void kF(
    const float* __restrict__ eo_in, const float* __restrict__ W_e,
    const float* __restrict__ att,
    const float* __restrict__ xl3, const float* __restrict__ xr3,
    const int2* __restrict__ ep, const int* __restrict__ off,
    const float* __restrict__ bias_gat, const float* __restrict__ glob,
    const int* __restrict__ batch, const float* __restrict__ W_n2,
    const float* __restrict__ b_n2,
    float* __restrict__ x_new, int niters)
{
    __shared__ float sWeI[32 * 96];   // 12 KB  [i][k*3+h] = W_e[i*96 + h*32 + k]
    __shared__ float2 sEo2[8][32];    // 2 KB dual staging (A,B)
    __shared__ float sWn[128 * 32];   // 16 KB node_mlp_2 weights
    __shared__ float sG[8][128];      // 4 KB tail staging
    int t = threadIdx.x;
    for (int f = t; f < 32 * 96; f += 256) {
        int i = f / 96, r = f - i * 96;
        int kk = r / 3, h = r - kk * 3;
        sWeI[f] = W_e[i * 96 + h * 32 + kk];
    }
    for (int f = t; f < 128 * 32; f += 256) sWn[f] = W_n2[f];
    __syncthreads();
    int k = t & 31, gid = t >> 5;
    float at0 = att[k], at1 = att[32 + k], at2 = att[64 + k];
    float bg0 = bias_gat[k], bg1 = bias_gat[32 + k], bg2 = bias_gat[64 + k];
    float bn = b_n2[k];
    const int k3 = k * 3;
    for (int it = 0; it < niters; ++it) {
        long n = ((long)blockIdx.x + (long)it * gridDim.x) * 8 + gid;
        if (n >= N_NODES) continue;
        int lo = off[n], hi = off[n + 1];
        long nb3 = n * HNO + k3;
        float xr0 = xr3[nb3], xr1 = xr3[nb3 + 1], xr2 = xr3[nb3 + 2];
        float a0 = 0.f, a1 = 0.f, a2 = 0.f;
        float d0 = 0.f, d1 = 0.f, d2 = 0.f;
        int deg = hi - lo;
        int steps = (deg + 1) >> 1;
        int eA = 0, sA = 0, eB = 0, sB = 0;
        int eA1 = 0, sA1 = 0, eB1 = 0, sB1 = 0;
        float eoAc = 0.f, eoBc = 0.f;
        float xlA0 = 0.f, xlA1 = 0.f, xlA2 = 0.f, xlB0 = 0.f, xlB1 = 0.f, xlB2 = 0.f;
        if (steps > 0) {
            int2 q = ep[lo]; eA = q.x; sA = q.y;
            if (lo + 1 < hi) { int2 r = ep[lo + 1]; eB = r.x; sB = r.y; }
            eoAc = eo_in[(long)eA * EO + k];
            eoBc = eo_in[(long)eB * EO + k];
            long a3 = (long)sA * HNO + k3, b3 = (long)sB * HNO + k3;
            xlA0 = xl3[a3]; xlA1 = xl3[a3 + 1]; xlA2 = xl3[a3 + 2];
            xlB0 = xl3[b3]; xlB1 = xl3[b3 + 1]; xlB2 = xl3[b3 + 2];
            if (lo + 2 < hi) { int2 q1 = ep[lo + 2]; eA1 = q1.x; sA1 = q1.y; }
            if (lo + 3 < hi) { int2 r1 = ep[lo + 3]; eB1 = r1.x; sB1 = r1.y; }
        }
        for (int st = 0; st < steps; ++st) {
            // prefetch next-pair data (clamped-id defaults harmless)
            float eoA_n = eo_in[(long)eA1 * EO + k];
            float eoB_n = eo_in[(long)eB1 * EO + k];
            long a3 = (long)sA1 * HNO + k3, b3 = (long)sB1 * HNO + k3;
            float xlA0n = xl3[a3], xlA1n = xl3[a3 + 1], xlA2n = xl3[a3 + 2];
            float xlB0n = xl3[b3], xlB1n = xl3[b3 + 1], xlB2n = xl3[b3 + 2];
            int eA2 = 0, sA2 = 0, eB2 = 0, sB2 = 0;
            int pA2 = lo + 2 * st + 4;
            if (pA2 < hi)     { int2 q2 = ep[pA2];     eA2 = q2.x; sA2 = q2.y; }
            if (pA2 + 1 < hi) { int2 r2 = ep[pA2 + 1]; eB2 = r2.x; sB2 = r2.y; }
            // ---- h = xl + xr + eo@We (dual; b96 weight reads) ----
            sEo2[gid][k] = make_float2(eoAc, eoBc);
            float hA0 = xlA0 + xr0, hA1 = xlA1 + xr1, hA2 = xlA2 + xr2;
            float hB0 = xlB0 + xr0, hB1 = xlB1 + xr1, hB2 = xlB2 + xr2;
            #pragma unroll 8
            for (int i = 0; i < 32; ++i) {
                float2 ov = sEo2[gid][i];
                const float* wp = &sWeI[i * 96 + k3];
                float w0 = wp[0], w1 = wp[1], w2v = wp[2];
                hA0 += ov.x * w0; hA1 += ov.x * w1; hA2 += ov.x * w2v;
                hB0 += ov.y * w0; hB1 += ov.y * w1; hB2 += ov.y * w2v;
            }
            float pA0 = (hA0 > 0.f ? hA0 : NEG * hA0) * at0;
            float pA1 = (hA1 > 0.f ? hA1 : NEG * hA1) * at1;
            float pA2v = (hA2 > 0.f ? hA2 : NEG * hA2) * at2;
            float pB0 = (hB0 > 0.f ? hB0 : NEG * hB0) * at0;
            float pB1 = (hB1 > 0.f ? hB1 : NEG * hB1) * at1;
            float pB2 = (hB2 > 0.f ? hB2 : NEG * hB2) * at2;
            #pragma unroll
            for (int m = 1; m <= 16; m <<= 1) {
                pA0 += __shfl_xor(pA0, m, 32); pA1 += __shfl_xor(pA1, m, 32); pA2v += __shfl_xor(pA2v, m, 32);
                pB0 += __shfl_xor(pB0, m, 32); pB1 += __shfl_xor(pB1, m, 32); pB2 += __shfl_xor(pB2, m, 32);
            }
            bool okB = (lo + 2 * st + 1) < hi;
            float exA0 = __expf(pA0), exA1 = __expf(pA1), exA2 = __expf(pA2v);
            float exB0 = 0.f, exB1 = 0.f, exB2 = 0.f;
            if (okB) { exB0 = __expf(pB0); exB1 = __expf(pB1); exB2 = __expf(pB2); }
            a0 += exA0 * xlA0; a1 += exA1 * xlA1; a2 += exA2 * xlA2;
            a0 += exB0 * xlB0; a1 += exB1 * xlB1; a2 += exB2 * xlB2;
            d0 += exA0 + exB0; d1 += exA1 + exB1; d2 += exA2 + exB2;
            // rotate pipeline
            eA = eA1; sA = sA1; eB = eB1; sB = sB1;
            eA1 = eA2; sA1 = sA2; eB1 = eB2; sB1 = sB2;
            eoAc = eoA_n; eoBc = eoB_n;
            xlA0 = xlA0n; xlA1 = xlA1n; xlA2 = xlA2n;
            xlB0 = xlB0n; xlB1 = xlB1n; xlB2 = xlB2n;
        }
        // ---- fused node_mlp_2 tail (planar gat layout in sG) ----
        float g0 = (d0 > 0.f ? a0 / d0 : 0.f) + bg0;
        float g1 = (d1 > 0.f ? a1 / d1 : 0.f) + bg1;
        float g2 = (d2 > 0.f ? a2 / d2 : 0.f) + bg2;
        float gg = glob[(long)batch[n] * GI + k];
        sG[gid][k] = g0; sG[gid][32 + k] = g1; sG[gid][64 + k] = g2; sG[gid][96 + k] = gg;
        float acc2 = bn;
        #pragma unroll 8
        for (int i = 0; i < 128; ++i) acc2 += sG[gid][i] * sWn[i * 32 + k];
        x_new[n * NO + k] = fmaxf(acc2, 0.f);
    }
}

// ---------------- K3: per-graph mean of x_new (batch sorted), then global MLP ----------------
__device__ __forceinline__ int lower_bound_dev(const int* __restrict__ a, int n, int v) {
    int lo = 0, hi = n;
    while (lo < hi) { int mid = (lo + hi) >> 1; if (a[mid] < v) lo = mid + 1; else hi = mid; }
    return lo;
}

__global__ __launch_bounds__(256) void k3_global(
    const float* __restrict__ x_new, const int* __restrict__ batch,
    const float* __restrict__ glob, const float* __restrict__ W_g,
    const float* __restrict__ b_g, float* __restrict__ u_new)
{
    __shared__ int s_lo, s_hi;
    __shared__ float s_part[8][32];
    __shared__ float s_mean[32];
    int g = blockIdx.x;
    if (threadIdx.x == 0) {
        s_lo = lower_bound_dev(batch, N_NODES, g);
        s_hi = lower_bound_dev(batch, N_NODES, g + 1);
    }
    __syncthreads();
    int lo = s_lo, hi = s_hi;
    int k = threadIdx.x & 31, c = threadIdx.x >> 5;
    float acc = 0.f;
    for (long n = lo + c; n < hi; n += 8) acc += x_new[n * NO + k];
    s_part[c][k] = acc;
    __syncthreads();
    if (threadIdx.x < 32) {
        float s = 0.f;
        #pragma unroll
        for (int c2 = 0; c2 < 8; ++c2) s += s_part[c2][k];
        int cnt = hi - lo;
        s_mean[k] = s / (float)(cnt > 0 ? cnt : 1);
    }
    __syncthreads();
    if (threadIdx.x < 32) {
        float acc2 = b_g[k];
        #pragma unroll
        for (int i = 0; i < 32; ++i) acc2 += glob[g * GI + i] * W_g[i * GO + k];
        #pragma unroll
        for (int i = 0; i < 32; ++i) acc2 += s_mean[i] * W_g[(32 + i) * GO + k];
        u_new[g * GO + k] = fmaxf(acc2, 0.f);
    }
}

extern "C" void kernel_launch(void* const* d_in, const int* in_sizes, int n_in,
                              void* d_out, int out_size, void* d_ws, size_t ws_size,
                              hipStream_t stream) {
    const float* x        = (const float*)d_in[0];
    const float* edge_attr= (const float*)d_in[1];
    const float* glob     = (const float*)d_in[2];
    const float* W_edge   = (const float*)d_in[3];
    const float* b_edge   = (const float*)d_in[4];
    const float* W_l      = (const float*)d_in[5];
    const float* b_l      = (const float*)d_in[6];
    const float* W_r      = (const float*)d_in[7];
    const float* b_r      = (const float*)d_in[8];
    const float* W_e      = (const float*)d_in[9];
    const float* att      = (const float*)d_in[10];
    const float* bias_gat = (const float*)d_in[11];
    const float* W_n2     = (const float*)d_in[12];
    const float* b_n2     = (const float*)d_in[13];
    const float* W_g      = (const float*)d_in[14];
    const float* b_g      = (const float*)d_in[15];
    const int* edge_index = (const int*)d_in[16];
    const int* batch      = (const int*)d_in[17];

    float* out   = (float*)d_out;
    float* x_new = out;                                    // N*32
    float* e_out = out + (size_t)N_NODES * NO;             // E*32
    float* u_new = e_out + (size_t)N_EDGES * EO;           // B*32

    // workspace layout (floats before ep sum to N*224 -> ep stays 8B-aligned)
    float*  ws    = (float*)d_ws;
    float*  xl3   = ws;                                    // N*96 (interleaved)
    float*  xr3   = xl3 + (size_t)N_NODES * HNO;           // N*96 (interleaved)
    float*  pre_e = xr3 + (size_t)N_NODES * HNO;           // N*32
    int2*   ep    = (int2*)(pre_e + (size_t)N_NODES * 32); // E int2
    int*    cnt   = (int*)(ep + (size_t)N_EDGES);          // N
    int*    off   = cnt + N_NODES;                         // N+1
    int*    cursor= off + N_NODES + 1;                     // N
    int*    bsum  = cursor + N_NODES;                      // 128

    hipMemsetAsync(cnt, 0, (size_t)N_NODES * sizeof(int), stream);

    // node transforms + histogram (xl3, xr3, pre_e; cnt via fire-and-forget atomics)
    int gridA = 1024;
    int groups64 = (N_NODES + 63) / 64;                    // 1563
    int itA = (groups64 + gridA - 1) / gridA;              // 2
    kA_node<<<gridA, 256, 0, stream>>>(x, edge_index, cnt, W_l, b_l, W_r, b_r,
                                       W_edge, b_edge, xl3, xr3, pre_e, itA);

    // CSR offsets (parallel scan)
    k_scan1<<<SCAN_BLKS, 1024, 0, stream>>>(cnt, bsum);
    k_scan2<<<1, 128, 0, stream>>>(bsum);
    k_scan3<<<SCAN_BLKS, 1024, 0, stream>>>(cnt, bsum, off, cursor);

    // edge MLP (coalesced e_out) + fused CSR scatter
    int gridE = 2048;
    int groupsE = (N_EDGES + 15) / 16;                     // 100000
    int itE = (groupsE + gridE - 1) / gridE;               // 49
    kEscat<<<gridE, 256, 0, stream>>>(edge_index, cursor, ep, pre_e, edge_attr,
                                      W_edge, e_out, itE);

    // attention pass + aggregation + node_mlp_2 (dual-edge, fused tail)
    int gridF = 2048;
    int groups8 = (N_NODES + 7) / 8;                       // 12500
    int itF = (groups8 + gridF - 1) / gridF;               // 7
    kF<<<gridF, 256, 0, stream>>>(e_out, W_e, att, xl3, xr3,
                                  ep, off, bias_gat, glob, batch, W_n2, b_n2,
                                  x_new, itF);

    k3_global<<<NB, 256, 0, stream>>>(x_new, batch, glob, W_g, b_g, u_new);
}